// Round 6
// baseline (321.380 us; speedup 1.0000x reference)
//
#include <hip/hip_runtime.h>
#include <math.h>

#define DIMC   256
#define NQ     4096
#define BATCH  4
#define NS     1024    // (H/SR)*(W/SR) = 32*32
#define WG     32
#define HG     32
#define NHEADS 8
#define HDIM   32
#define SCALE_ATTN 0.17677669529663687f  // 32^-0.5

typedef _Float16 f16;
typedef __attribute__((ext_vector_type(8))) __bf16    bf16x8;
typedef __attribute__((ext_vector_type(8))) _Float16  f16x8;
typedef __attribute__((ext_vector_type(4))) _Float16  f16x4;
typedef __attribute__((ext_vector_type(4))) float     f32x4;

#define MFMA16B(A, B, C) __builtin_amdgcn_mfma_f32_16x16x32_bf16((A), (B), (C), 0, 0, 0)
#define MFMA16F(A, B, C) __builtin_amdgcn_mfma_f32_16x16x32_f16((A), (B), (C), 0, 0, 0)

static __device__ __forceinline__ unsigned short bf16_hi(float v) {
    return __builtin_bit_cast(unsigned short, (__bf16)v);
}

// ---------------- scatter: token2map segment-sum ----------------
__global__ __launch_bounds__(DIMC) void scatter_kernel(
    const float* __restrict__ xsrc, const float* __restrict__ loc,
    const float* __restrict__ csrc, float* __restrict__ feat,
    float* __restrict__ cnt, float* __restrict__ confsum)
{
    int token = blockIdx.x;          // B*NQ tokens
    int b = token >> 12;             // NQ = 4096
    int c = threadIdx.x;
    float lx = loc[token * 2 + 0];
    float ly = loc[token * 2 + 1];
    lx = fminf(fmaxf(lx, 0.f), 1.f) * (float)(WG - 1);
    ly = fminf(fmaxf(ly, 0.f), 1.f) * (float)(HG - 1);
    int ix = (int)rintf(lx);         // round-half-even, matches jnp.round
    int iy = (int)rintf(ly);
    int cell = b * NS + iy * WG + ix;
    atomicAdd(&feat[cell * DIMC + c], xsrc[token * DIMC + c]);
    if (c == 0) {
        atomicAdd(&cnt[cell], 1.f);
        atomicAdd(&confsum[cell], csrc[token]);
    }
}

// ---------------- finalize: feat /= (cnt+eps), mask; conf map ----------------
__global__ __launch_bounds__(DIMC) void featfin_kernel(
    const float* __restrict__ cnt, const float* __restrict__ confsum,
    float* __restrict__ feat, float* __restrict__ conf)
{
    int m = blockIdx.x;              // B*NS cells
    int c = threadIdx.x;
    float cv = cnt[m];
    float inv = (cv > 0.f) ? 1.f / (cv + 1e-6f) : 0.f;
    feat[m * DIMC + c] *= inv;
    if (c == 0) conf[m] = confsum[m] * inv;
}

// ---------------- weight prep: Wsr,Wv -> bf16 hi/lo; Wq,Wk,Wp -> f16 ----------------
__global__ __launch_bounds__(256) void wprep_kernel(
    const float* __restrict__ Wsr, const float* __restrict__ Wv,
    const float* __restrict__ Wq, const float* __restrict__ Wk,
    const float* __restrict__ Wp,
    unsigned short* __restrict__ wsrh, unsigned short* __restrict__ wsrl,
    unsigned short* __restrict__ wvh, unsigned short* __restrict__ wvl,
    f16* __restrict__ wq16, f16* __restrict__ wk16, f16* __restrict__ wp16)
{
    int i = (blockIdx.x * 256 + threadIdx.x) * 4;   // grid.x = 64 -> 65536 elems
    int m = blockIdx.y;
    if (m < 2) {
        const float* W = m ? Wv : Wsr;
        unsigned short* H = m ? wvh : wsrh;
        unsigned short* L = m ? wvl : wsrl;
        float4 v = *(const float4*)(W + i);
        float vv[4] = {v.x, v.y, v.z, v.w};
        ushort4 h, l;
        unsigned short* hp = &h.x; unsigned short* lp = &l.x;
        #pragma unroll
        for (int j = 0; j < 4; j++) {
            __bf16 hb = (__bf16)vv[j];
            hp[j] = __builtin_bit_cast(unsigned short, hb);
            lp[j] = bf16_hi(vv[j] - (float)hb);
        }
        *(ushort4*)(H + i) = h;
        *(ushort4*)(L + i) = l;
    } else {
        const float* W = (m == 2) ? Wq : (m == 3) ? Wk : Wp;
        f16* O = (m == 2) ? wq16 : (m == 3) ? wk16 : wp16;
        float4 v = *(const float4*)(W + i);
        f16x4 h = {(f16)v.x, (f16)v.y, (f16)v.z, (f16)v.w};
        *(f16x4*)(O + i) = h;
    }
}

// ---------------- bf16x2-split MFMA GEMM (exact-ish): Wsr, Wv ----------------
// EPI: 0 = f32 row-major; 2 = fp16 hi/lo transposed (V): out[(b*256+c)*1024+key].
template <int EPI, bool HASBIAS>
__global__ __launch_bounds__(256) void mfma_gemm_kernel(
    const float* __restrict__ A,
    const unsigned short* __restrict__ Whi, const unsigned short* __restrict__ Wlo,
    const float* __restrict__ bias, float* __restrict__ outF,
    f16* __restrict__ o16a, f16* __restrict__ o16b)
{
    int r0 = blockIdx.x * 64;
    int c0 = blockIdx.y * 128;
    int wave = threadIdx.x >> 6;
    int lane = threadIdx.x & 63;
    int s = lane & 15, g = lane >> 4;

    int arow = r0 + wave * 16 + s;              // A-frag row for this lane
    const float* ap = A + (size_t)arow * DIMC + 8 * g;

    f32x4 acc[8];
    #pragma unroll
    for (int cf = 0; cf < 8; cf++) {
        float bv = HASBIAS ? bias[c0 + cf * 16 + s] : 0.f;
        acc[cf] = (f32x4){bv, bv, bv, bv};
    }

    #pragma unroll
    for (int kk = 0; kk < 8; kk++) {
        float4 a0 = *(const float4*)(ap + kk * 32);
        float4 a1 = *(const float4*)(ap + kk * 32 + 4);
        float av[8] = {a0.x, a0.y, a0.z, a0.w, a1.x, a1.y, a1.z, a1.w};
        bf16x8 ah, al;
        #pragma unroll
        for (int j = 0; j < 8; j++) {
            __bf16 hb = (__bf16)av[j];
            ah[j] = hb;
            al[j] = (__bf16)(av[j] - (float)hb);
        }
        #pragma unroll
        for (int cf = 0; cf < 8; cf++) {
            size_t woff = (size_t)(c0 + cf * 16 + s) * DIMC + kk * 32 + 8 * g;
            bf16x8 bh = *(const bf16x8*)(Whi + woff);
            bf16x8 bl = *(const bf16x8*)(Wlo + woff);
            acc[cf] = MFMA16B(ah, bh, acc[cf]);
            acc[cf] = MFMA16B(al, bh, acc[cf]);
            acc[cf] = MFMA16B(ah, bl, acc[cf]);
        }
    }

    int rbase = r0 + wave * 16 + 4 * g;         // output rows rbase..rbase+3
    if (EPI == 0) {
        #pragma unroll
        for (int cf = 0; cf < 8; cf++) {
            int c = c0 + cf * 16 + s;
            #pragma unroll
            for (int r = 0; r < 4; r++)
                outF[(size_t)(rbase + r) * DIMC + c] = acc[cf][r];
        }
    } else {
        int b = rbase >> 10;                    // 64-row blocks never cross batch
        int key0 = rbase & 1023;
        #pragma unroll
        for (int cf = 0; cf < 8; cf++) {
            int c = c0 + cf * 16 + s;
            f16x4 h, l;
            #pragma unroll
            for (int r = 0; r < 4; r++) {
                float v = acc[cf][r];
                f16 hb = (f16)v;
                h[r] = hb;
                l[r] = (f16)(v - (float)hb);
            }
            size_t off = ((size_t)(b * DIMC + c)) * NS + key0;
            *(f16x4*)(o16a + off) = h;
            *(f16x4*)(o16b + off) = l;
        }
    }
}

// ---------------- single-product fp16 GEMM: Wq, Wk, Wp ----------------
// A16: A is f16 (else fp32, cvt in regs). OUT16: f16 out (else f32).
template <bool A16, bool OUT16, bool HASBIAS>
__global__ __launch_bounds__(256) void gemm16_kernel(
    const void* __restrict__ Ain, const f16* __restrict__ W,
    const float* __restrict__ bias, float* __restrict__ outF,
    f16* __restrict__ out16)
{
    int r0 = blockIdx.x * 64;
    int c0 = blockIdx.y * 128;
    int wave = threadIdx.x >> 6;
    int lane = threadIdx.x & 63;
    int s = lane & 15, g = lane >> 4;
    int arow = r0 + wave * 16 + s;

    f32x4 acc[8];
    #pragma unroll
    for (int cf = 0; cf < 8; cf++) {
        float bv = HASBIAS ? bias[c0 + cf * 16 + s] : 0.f;
        acc[cf] = (f32x4){bv, bv, bv, bv};
    }

    #pragma unroll
    for (int kk = 0; kk < 8; kk++) {
        f16x8 a;
        if (A16) {
            a = *(const f16x8*)((const f16*)Ain + (size_t)arow * DIMC + kk * 32 + 8 * g);
        } else {
            const float* ap = (const float*)Ain + (size_t)arow * DIMC + kk * 32 + 8 * g;
            float4 a0 = *(const float4*)ap;
            float4 a1 = *(const float4*)(ap + 4);
            a = (f16x8){(f16)a0.x, (f16)a0.y, (f16)a0.z, (f16)a0.w,
                        (f16)a1.x, (f16)a1.y, (f16)a1.z, (f16)a1.w};
        }
        #pragma unroll
        for (int cf = 0; cf < 8; cf++) {
            f16x8 bfrag = *(const f16x8*)(W + (size_t)(c0 + cf * 16 + s) * DIMC + kk * 32 + 8 * g);
            acc[cf] = MFMA16F(a, bfrag, acc[cf]);
        }
    }

    int rbase = r0 + wave * 16 + 4 * g;
    #pragma unroll
    for (int cf = 0; cf < 8; cf++) {
        int c = c0 + cf * 16 + s;
        #pragma unroll
        for (int r = 0; r < 4; r++) {
            if (OUT16) out16[(size_t)(rbase + r) * DIMC + c] = (f16)acc[cf][r];
            else       outF [(size_t)(rbase + r) * DIMC + c] = acc[cf][r];
        }
    }
}

// ---------------- layernorm in place over last dim ----------------
__global__ __launch_bounds__(DIMC) void ln_kernel(
    float* __restrict__ xs, const float* __restrict__ g, const float* __restrict__ b)
{
    int m = blockIdx.x;
    int c = threadIdx.x;
    float v = xs[(size_t)m * DIMC + c];
    float s = v, q = v * v;
    #pragma unroll
    for (int off = 32; off > 0; off >>= 1) {
        s += __shfl_xor(s, off);
        q += __shfl_xor(q, off);
    }
    __shared__ float sh1[4], sh2[4];
    int wid = c >> 6, lane = c & 63;
    if (lane == 0) { sh1[wid] = s; sh2[wid] = q; }
    __syncthreads();
    s = sh1[0] + sh1[1] + sh1[2] + sh1[3];
    q = sh2[0] + sh2[1] + sh2[2] + sh2[3];
    float mu  = s * (1.f / DIMC);
    float var = q * (1.f / DIMC) - mu * mu;
    xs[(size_t)m * DIMC + c] = (v - mu) * rsqrtf(var + 1e-5f) * g[c] + b[c];
}

// ---------------- MFMA flash attention (fp16, swapped-operand) ----------------
// 16 queries per wave, 2048 blocks (8 waves/SIMD). Q,K,P fp16 single;
// V fp16 hi+lo; exact skip-rescale; f16 output.
__global__ __launch_bounds__(256) void attn_mfma_kernel(
    const f16* __restrict__ qbuf, const f16* __restrict__ kbuf,
    const f16* __restrict__ vthi, const f16* __restrict__ vtlo,
    const float* __restrict__ conf, f16* __restrict__ abuf)
{
    int blk  = blockIdx.x;            // B*H*(NQ/64) = 2048
    int qt   = blk & 63;              // NQ/64 = 64
    int bh   = blk >> 6;
    int hh   = bh & (NHEADS - 1);
    int b    = bh >> 3;
    int wave = threadIdx.x >> 6;
    int lane = threadIdx.x & 63;
    int s = lane & 15, g = lane >> 4;
    int q0 = qt * 64 + wave * 16;

    // Q fragment (B-operand for S^T): lane holds Q[q0+s][d=8g+j]
    f16x8 qh = *(const f16x8*)(qbuf +
        ((size_t)(b * NQ + q0 + s)) * DIMC + hh * HDIM + 8 * g);

    f32x4 oacc[2];
    oacc[0] = (f32x4){0.f, 0.f, 0.f, 0.f};
    oacc[1] = (f32x4){0.f, 0.f, 0.f, 0.f};
    float mrun = -INFINITY, lrun = 0.f;

    const f16* khb = kbuf + ((size_t)(b * NS)) * DIMC + hh * HDIM + 8 * g;
    const f16* vhb = vthi + ((size_t)(bh * HDIM)) * NS + 8 * g;
    const f16* vlb = vtlo + ((size_t)(bh * HDIM)) * NS + 8 * g;
    const float* cfb = conf + b * NS + 4 * g;

    int addr0 = (s + ((g & 1) << 5)) << 2;   // src lane s + 32*(g&1), bytes
    int addr1 = addr0 + 64;                  // +16 lanes
    bool hiHalf = (g >= 2);                  // source frag = g>>1

    for (int k0 = 0; k0 < NS; k0 += 32) {
        // K fragments (A-operand): lane holds K[k0+16f+s][d=8g+j]
        f16x8 kh[2];
        #pragma unroll
        for (int f = 0; f < 2; f++)
            kh[f] = *(const f16x8*)(khb + ((size_t)(k0 + 16 * f + s)) * DIMC);
        // V^T fragments (A-operand for PV): lane holds Vt[16m+s][k0+8g+j]
        f16x8 vh[2], vl[2];
        #pragma unroll
        for (int m = 0; m < 2; m++) {
            size_t off = ((size_t)(16 * m + s)) * NS + k0;
            vh[m] = *(const f16x8*)(vhb + off);
            vl[m] = *(const f16x8*)(vlb + off);
        }
        // conf for this lane's score slots: keys k0 + 16f + 4g + r
        float4 cq[2];
        #pragma unroll
        for (int f = 0; f < 2; f++)
            cq[f] = *(const float4*)(cfb + k0 + 16 * f);

        // S^T = K * Q^T (single fp16 product)
        f32x4 sa[2];
        #pragma unroll
        for (int f = 0; f < 2; f++) {
            f32x4 z = (f32x4){0.f, 0.f, 0.f, 0.f};
            sa[f] = MFMA16F(kh[f], qh, z);
        }
        float sc[2][4], mc = -INFINITY;
        #pragma unroll
        for (int f = 0; f < 2; f++) {
            const float* cp = &cq[f].x;
            #pragma unroll
            for (int r = 0; r < 4; r++) {
                sc[f][r] = sa[f][r] * SCALE_ATTN + cp[r];
                mc = fmaxf(mc, sc[f][r]);
            }
        }
        mc = fmaxf(mc, __shfl_xor(mc, 16));
        mc = fmaxf(mc, __shfl_xor(mc, 32));
        if (__any(mc > mrun)) {              // exact skip: corr==1 otherwise
            float mnew = fmaxf(mrun, mc);
            float corr = __expf(mrun - mnew);  // exp(-inf)=0 first chunk
            mrun = mnew;
            lrun *= corr;
            #pragma unroll
            for (int m = 0; m < 2; m++)
                #pragma unroll
                for (int r = 0; r < 4; r++)
                    oacc[m][r] *= corr;
        }
        float p[2][4], ls = 0.f;
        #pragma unroll
        for (int f = 0; f < 2; f++)
            #pragma unroll
            for (int r = 0; r < 4; r++) {
                p[f][r] = __expf(sc[f][r] - mrun);
                ls += p[f][r];
            }
        ls += __shfl_xor(ls, 16);
        ls += __shfl_xor(ls, 32);
        lrun += ls;

        // P -> fp16 packed words: w[f][r2] = keys {16f+4g+2r2, +1}
        unsigned w[2][2];
        #pragma unroll
        for (int f = 0; f < 2; f++)
            #pragma unroll
            for (int r2 = 0; r2 < 2; r2++)
                w[f][r2] = __builtin_bit_cast(unsigned,
                    __builtin_amdgcn_cvt_pkrtz(p[f][2 * r2], p[f][2 * r2 + 1]));
        // gather to PV B-operand: lane gets P^T[key=8g+2j,2j+1][q=s]
        unsigned bw[4];
        {
            int a0 = __builtin_amdgcn_ds_bpermute(addr0, (int)w[0][0]);
            int a0h = __builtin_amdgcn_ds_bpermute(addr0, (int)w[1][0]);
            bw[0] = (unsigned)(hiHalf ? a0h : a0);
            int a1 = __builtin_amdgcn_ds_bpermute(addr0, (int)w[0][1]);
            int a1h = __builtin_amdgcn_ds_bpermute(addr0, (int)w[1][1]);
            bw[1] = (unsigned)(hiHalf ? a1h : a1);
            int a2 = __builtin_amdgcn_ds_bpermute(addr1, (int)w[0][0]);
            int a2h = __builtin_amdgcn_ds_bpermute(addr1, (int)w[1][0]);
            bw[2] = (unsigned)(hiHalf ? a2h : a2);
            int a3 = __builtin_amdgcn_ds_bpermute(addr1, (int)w[0][1]);
            int a3h = __builtin_amdgcn_ds_bpermute(addr1, (int)w[1][1]);
            bw[3] = (unsigned)(hiHalf ? a3h : a3);
        }
        union { unsigned u[4]; f16x8 v; } Bv;
        #pragma unroll
        for (int j = 0; j < 4; j++) Bv.u[j] = bw[j];
        // O^T += V^T * P^T (Vhi + Vlo products)
        #pragma unroll
        for (int m = 0; m < 2; m++) {
            oacc[m] = MFMA16F(vh[m], Bv.v, oacc[m]);
            oacc[m] = MFMA16F(vl[m], Bv.v, oacc[m]);
        }
    } // chunk

    // epilogue: oacc[m][r] = O^T[d=16m+4g+r][q=q0+s]; f16 out
    float invl = 1.f / lrun;
    f16* orow = abuf + ((size_t)(b * NQ + q0 + s)) * DIMC + hh * HDIM;
    #pragma unroll
    for (int m = 0; m < 2; m++) {
        f16x4 o;
        #pragma unroll
        for (int r = 0; r < 4; r++) o[r] = (f16)(oacc[m][r] * invl);
        *(f16x4*)(orow + 16 * m + 4 * g) = o;
    }
}

extern "C" void kernel_launch(void* const* d_in, const int* in_sizes, int n_in,
                              void* d_out, int out_size, void* d_ws, size_t ws_size,
                              hipStream_t stream)
{
    (void)in_sizes; (void)n_in; (void)out_size; (void)ws_size;
    const float* x    = (const float*)d_in[0];
    const float* xsrc = (const float*)d_in[1];
    const float* loc  = (const float*)d_in[2];
    const float* csrc = (const float*)d_in[3];
    const float* Wq   = (const float*)d_in[4];
    const float* Wk   = (const float*)d_in[5];
    const float* Wv   = (const float*)d_in[6];
    const float* Wsr  = (const float*)d_in[7];
    const float* bsr  = (const float*)d_in[8];
    const float* lng  = (const float*)d_in[9];
    const float* lnb  = (const float*)d_in[10];
    const float* Wp   = (const float*)d_in[11];
    const float* bp   = (const float*)d_in[12];
    // d_in[13]=H(64), d_in[14]=W(64): fixed by setup_inputs; h=w=32 hardcoded.

    const int MS = BATCH * NS * DIMC;     // 1,048,576
    const int MQ = BATCH * NQ * DIMC;     // 4,194,304
    const int WSZ = DIMC * DIMC;          // 65,536

    float* ws      = (float*)d_ws;
    float* feat    = ws;                  // MS f32
    float* xs      = feat + MS;           // MS f32
    float* cnt     = xs + MS;             // 4096
    float* confsum = cnt + BATCH * NS;    // 4096
    float* conf    = confsum + BATCH * NS;// 4096
    f16* q16    = (f16*)(conf + BATCH * NS);  // MQ f16
    f16* k16    = q16 + MQ;               // MS f16
    f16* vthi16 = k16 + MS;               // MS f16
    f16* vtlo16 = vthi16 + MS;            // MS f16
    f16* abuf16 = vtlo16 + MS;            // MQ f16
    unsigned short* wsrh = (unsigned short*)(abuf16 + MQ);  // 4 x WSZ bf16
    unsigned short* wsrl = wsrh + WSZ;
    unsigned short* wvh  = wsrl + WSZ;
    unsigned short* wvl  = wvh  + WSZ;
    f16* wq16 = (f16*)(wvl + WSZ);        // 3 x WSZ f16
    f16* wk16 = wq16 + WSZ;
    f16* wp16 = wk16 + WSZ;               // total ~31 MB
    float* outp = (float*)d_out;

    hipMemsetAsync(feat, 0, (size_t)MS * sizeof(float), stream);
    hipMemsetAsync(cnt, 0, (size_t)(2 * BATCH * NS) * sizeof(float), stream);

    wprep_kernel<<<dim3(64, 5), 256, 0, stream>>>(
        Wsr, Wv, Wq, Wk, Wp, wsrh, wsrl, wvh, wvl, wq16, wk16, wp16);
    scatter_kernel<<<BATCH * NQ, DIMC, 0, stream>>>(xsrc, loc, csrc, feat, cnt, confsum);
    featfin_kernel<<<BATCH * NS, DIMC, 0, stream>>>(cnt, confsum, feat, conf);
    mfma_gemm_kernel<0, true ><<<dim3(BATCH * NS / 64, 2), 256, 0, stream>>>(
        feat, wsrh, wsrl, bsr, xs, nullptr, nullptr);
    ln_kernel<<<BATCH * NS, DIMC, 0, stream>>>(xs, lng, lnb);
    gemm16_kernel<false, true, false><<<dim3(BATCH * NS / 64, 2), 256, 0, stream>>>(
        xs, wk16, nullptr, nullptr, k16);
    mfma_gemm_kernel<2, false><<<dim3(BATCH * NS / 64, 2), 256, 0, stream>>>(
        xs, wvh, wvl, nullptr, nullptr, vthi16, vtlo16);
    gemm16_kernel<false, true, false><<<dim3(BATCH * NQ / 64, 2), 256, 0, stream>>>(
        x, wq16, nullptr, nullptr, q16);
    attn_mfma_kernel<<<BATCH * NHEADS * (NQ / 64), 256, 0, stream>>>(
        q16, k16, vthi16, vtlo16, conf, abuf16);
    gemm16_kernel<true, false, true><<<dim3(BATCH * NQ / 64, 2), 256, 0, stream>>>(
        abuf16, wp16, bp, outp, nullptr);
}

// Round 7
// 253.417 us; speedup vs baseline: 1.2682x; 1.2682x over previous
//
#include <hip/hip_runtime.h>
#include <math.h>

#define DIMC   256
#define NQ     4096
#define BATCH  4
#define NS     1024    // (H/SR)*(W/SR) = 32*32
#define WG     32
#define HG     32
#define NHEADS 8
#define HDIM   32
#define SCALE_ATTN 0.17677669529663687f  // 32^-0.5

typedef _Float16 f16;
typedef __attribute__((ext_vector_type(8))) __bf16    bf16x8;
typedef __attribute__((ext_vector_type(8))) _Float16  f16x8;
typedef __attribute__((ext_vector_type(4))) _Float16  f16x4;
typedef __attribute__((ext_vector_type(4))) float     f32x4;

#define MFMA16B(A, B, C) __builtin_amdgcn_mfma_f32_16x16x32_bf16((A), (B), (C), 0, 0, 0)
#define MFMA16F(A, B, C) __builtin_amdgcn_mfma_f32_16x16x32_f16((A), (B), (C), 0, 0, 0)

static __device__ __forceinline__ unsigned short bf16_hi(float v) {
    return __builtin_bit_cast(unsigned short, (__bf16)v);
}

// ---------------- scatter: token2map segment-sum ----------------
__global__ __launch_bounds__(DIMC) void scatter_kernel(
    const float* __restrict__ xsrc, const float* __restrict__ loc,
    const float* __restrict__ csrc, float* __restrict__ feat,
    float* __restrict__ cnt, float* __restrict__ confsum)
{
    int token = blockIdx.x;          // B*NQ tokens
    int b = token >> 12;             // NQ = 4096
    int c = threadIdx.x;
    float lx = loc[token * 2 + 0];
    float ly = loc[token * 2 + 1];
    lx = fminf(fmaxf(lx, 0.f), 1.f) * (float)(WG - 1);
    ly = fminf(fmaxf(ly, 0.f), 1.f) * (float)(HG - 1);
    int ix = (int)rintf(lx);         // round-half-even, matches jnp.round
    int iy = (int)rintf(ly);
    int cell = b * NS + iy * WG + ix;
    atomicAdd(&feat[cell * DIMC + c], xsrc[token * DIMC + c]);
    if (c == 0) {
        atomicAdd(&cnt[cell], 1.f);
        atomicAdd(&confsum[cell], csrc[token]);
    }
}

// ---------------- finalize: feat /= (cnt+eps), mask; conf map ----------------
__global__ __launch_bounds__(DIMC) void featfin_kernel(
    const float* __restrict__ cnt, const float* __restrict__ confsum,
    float* __restrict__ feat, float* __restrict__ conf)
{
    int m = blockIdx.x;              // B*NS cells
    int c = threadIdx.x;
    float cv = cnt[m];
    float inv = (cv > 0.f) ? 1.f / (cv + 1e-6f) : 0.f;
    feat[m * DIMC + c] *= inv;
    if (c == 0) conf[m] = confsum[m] * inv;
}

// ---------------- weight prep: Wsr,Wv -> bf16 hi/lo; Wq,Wk,Wp -> f16 ----------------
__global__ __launch_bounds__(256) void wprep_kernel(
    const float* __restrict__ Wsr, const float* __restrict__ Wv,
    const float* __restrict__ Wq, const float* __restrict__ Wk,
    const float* __restrict__ Wp,
    unsigned short* __restrict__ wsrh, unsigned short* __restrict__ wsrl,
    unsigned short* __restrict__ wvh, unsigned short* __restrict__ wvl,
    f16* __restrict__ wq16, f16* __restrict__ wk16, f16* __restrict__ wp16)
{
    int i = (blockIdx.x * 256 + threadIdx.x) * 4;   // grid.x = 64 -> 65536 elems
    int m = blockIdx.y;
    if (m < 2) {
        const float* W = m ? Wv : Wsr;
        unsigned short* H = m ? wvh : wsrh;
        unsigned short* L = m ? wvl : wsrl;
        float4 v = *(const float4*)(W + i);
        float vv[4] = {v.x, v.y, v.z, v.w};
        ushort4 h, l;
        unsigned short* hp = &h.x; unsigned short* lp = &l.x;
        #pragma unroll
        for (int j = 0; j < 4; j++) {
            __bf16 hb = (__bf16)vv[j];
            hp[j] = __builtin_bit_cast(unsigned short, hb);
            lp[j] = bf16_hi(vv[j] - (float)hb);
        }
        *(ushort4*)(H + i) = h;
        *(ushort4*)(L + i) = l;
    } else {
        const float* W = (m == 2) ? Wq : (m == 3) ? Wk : Wp;
        f16* O = (m == 2) ? wq16 : (m == 3) ? wk16 : wp16;
        float4 v = *(const float4*)(W + i);
        f16x4 h = {(f16)v.x, (f16)v.y, (f16)v.z, (f16)v.w};
        *(f16x4*)(O + i) = h;
    }
}

// ---------------- bf16x2-split MFMA GEMM (exact-ish): Wsr, Wv ----------------
// EPI: 0 = f32 row-major; 2 = fp16 hi/lo transposed (V): out[(b*256+c)*1024+key].
template <int EPI, bool HASBIAS>
__global__ __launch_bounds__(256) void mfma_gemm_kernel(
    const float* __restrict__ A,
    const unsigned short* __restrict__ Whi, const unsigned short* __restrict__ Wlo,
    const float* __restrict__ bias, float* __restrict__ outF,
    f16* __restrict__ o16a, f16* __restrict__ o16b)
{
    int r0 = blockIdx.x * 64;
    int c0 = blockIdx.y * 128;
    int wave = threadIdx.x >> 6;
    int lane = threadIdx.x & 63;
    int s = lane & 15, g = lane >> 4;

    int arow = r0 + wave * 16 + s;              // A-frag row for this lane
    const float* ap = A + (size_t)arow * DIMC + 8 * g;

    f32x4 acc[8];
    #pragma unroll
    for (int cf = 0; cf < 8; cf++) {
        float bv = HASBIAS ? bias[c0 + cf * 16 + s] : 0.f;
        acc[cf] = (f32x4){bv, bv, bv, bv};
    }

    #pragma unroll
    for (int kk = 0; kk < 8; kk++) {
        float4 a0 = *(const float4*)(ap + kk * 32);
        float4 a1 = *(const float4*)(ap + kk * 32 + 4);
        float av[8] = {a0.x, a0.y, a0.z, a0.w, a1.x, a1.y, a1.z, a1.w};
        bf16x8 ah, al;
        #pragma unroll
        for (int j = 0; j < 8; j++) {
            __bf16 hb = (__bf16)av[j];
            ah[j] = hb;
            al[j] = (__bf16)(av[j] - (float)hb);
        }
        #pragma unroll
        for (int cf = 0; cf < 8; cf++) {
            size_t woff = (size_t)(c0 + cf * 16 + s) * DIMC + kk * 32 + 8 * g;
            bf16x8 bh = *(const bf16x8*)(Whi + woff);
            bf16x8 bl = *(const bf16x8*)(Wlo + woff);
            acc[cf] = MFMA16B(ah, bh, acc[cf]);
            acc[cf] = MFMA16B(al, bh, acc[cf]);
            acc[cf] = MFMA16B(ah, bl, acc[cf]);
        }
    }

    int rbase = r0 + wave * 16 + 4 * g;         // output rows rbase..rbase+3
    if (EPI == 0) {
        #pragma unroll
        for (int cf = 0; cf < 8; cf++) {
            int c = c0 + cf * 16 + s;
            #pragma unroll
            for (int r = 0; r < 4; r++)
                outF[(size_t)(rbase + r) * DIMC + c] = acc[cf][r];
        }
    } else {
        int b = rbase >> 10;                    // 64-row blocks never cross batch
        int key0 = rbase & 1023;
        #pragma unroll
        for (int cf = 0; cf < 8; cf++) {
            int c = c0 + cf * 16 + s;
            f16x4 h, l;
            #pragma unroll
            for (int r = 0; r < 4; r++) {
                float v = acc[cf][r];
                f16 hb = (f16)v;
                h[r] = hb;
                l[r] = (f16)(v - (float)hb);
            }
            size_t off = ((size_t)(b * DIMC + c)) * NS + key0;
            *(f16x4*)(o16a + off) = h;
            *(f16x4*)(o16b + off) = l;
        }
    }
}

// ---------------- single-product fp16 GEMM: Wq, Wk, Wp ----------------
// A16: A is f16 (else fp32, cvt in regs). OUT16: f16 out (else f32).
template <bool A16, bool OUT16, bool HASBIAS>
__global__ __launch_bounds__(256) void gemm16_kernel(
    const void* __restrict__ Ain, const f16* __restrict__ W,
    const float* __restrict__ bias, float* __restrict__ outF,
    f16* __restrict__ out16)
{
    int r0 = blockIdx.x * 64;
    int c0 = blockIdx.y * 128;
    int wave = threadIdx.x >> 6;
    int lane = threadIdx.x & 63;
    int s = lane & 15, g = lane >> 4;
    int arow = r0 + wave * 16 + s;

    f32x4 acc[8];
    #pragma unroll
    for (int cf = 0; cf < 8; cf++) {
        float bv = HASBIAS ? bias[c0 + cf * 16 + s] : 0.f;
        acc[cf] = (f32x4){bv, bv, bv, bv};
    }

    #pragma unroll
    for (int kk = 0; kk < 8; kk++) {
        f16x8 a;
        if (A16) {
            a = *(const f16x8*)((const f16*)Ain + (size_t)arow * DIMC + kk * 32 + 8 * g);
        } else {
            const float* ap = (const float*)Ain + (size_t)arow * DIMC + kk * 32 + 8 * g;
            float4 a0 = *(const float4*)ap;
            float4 a1 = *(const float4*)(ap + 4);
            a = (f16x8){(f16)a0.x, (f16)a0.y, (f16)a0.z, (f16)a0.w,
                        (f16)a1.x, (f16)a1.y, (f16)a1.z, (f16)a1.w};
        }
        #pragma unroll
        for (int cf = 0; cf < 8; cf++) {
            f16x8 bfrag = *(const f16x8*)(W + (size_t)(c0 + cf * 16 + s) * DIMC + kk * 32 + 8 * g);
            acc[cf] = MFMA16F(a, bfrag, acc[cf]);
        }
    }

    int rbase = r0 + wave * 16 + 4 * g;
    #pragma unroll
    for (int cf = 0; cf < 8; cf++) {
        int c = c0 + cf * 16 + s;
        #pragma unroll
        for (int r = 0; r < 4; r++) {
            if (OUT16) out16[(size_t)(rbase + r) * DIMC + c] = (f16)acc[cf][r];
            else       outF [(size_t)(rbase + r) * DIMC + c] = acc[cf][r];
        }
    }
}

// ---------------- layernorm in place over last dim ----------------
__global__ __launch_bounds__(DIMC) void ln_kernel(
    float* __restrict__ xs, const float* __restrict__ g, const float* __restrict__ b)
{
    int m = blockIdx.x;
    int c = threadIdx.x;
    float v = xs[(size_t)m * DIMC + c];
    float s = v, q = v * v;
    #pragma unroll
    for (int off = 32; off > 0; off >>= 1) {
        s += __shfl_xor(s, off);
        q += __shfl_xor(q, off);
    }
    __shared__ float sh1[4], sh2[4];
    int wid = c >> 6, lane = c & 63;
    if (lane == 0) { sh1[wid] = s; sh2[wid] = q; }
    __syncthreads();
    s = sh1[0] + sh1[1] + sh1[2] + sh1[3];
    q = sh2[0] + sh2[1] + sh2[2] + sh2[3];
    float mu  = s * (1.f / DIMC);
    float var = q * (1.f / DIMC) - mu * mu;
    xs[(size_t)m * DIMC + c] = (v - mu) * rsqrtf(var + 1e-5f) * g[c] + b[c];
}

// ---------------- MFMA flash attention (fp16, swapped-operand) ----------------
// 32 queries/wave (2 qf frags), 64-key batched inner loop for ILP.
// Q,K,P fp16 single; V fp16 hi+lo; exact skip-rescale; f16 output.
__global__ __launch_bounds__(256) void attn_mfma_kernel(
    const f16* __restrict__ qbuf, const f16* __restrict__ kbuf,
    const f16* __restrict__ vthi, const f16* __restrict__ vtlo,
    const float* __restrict__ conf, f16* __restrict__ abuf)
{
    int blk  = blockIdx.x;            // B*H*(NQ/128) = 1024
    int qt   = blk & 31;              // NQ/128 = 32
    int bh   = blk >> 5;
    int hh   = bh & (NHEADS - 1);
    int b    = bh >> 3;
    int wave = threadIdx.x >> 6;
    int lane = threadIdx.x & 63;
    int s = lane & 15, g = lane >> 4;
    int q0 = qt * 128 + wave * 32;

    // Q fragments (B-operand for S^T): lane holds Q[q0+qf*16+s][d=8g+j]
    f16x8 qh[2];
    #pragma unroll
    for (int qf = 0; qf < 2; qf++)
        qh[qf] = *(const f16x8*)(qbuf +
            ((size_t)(b * NQ + q0 + qf * 16 + s)) * DIMC + hh * HDIM + 8 * g);

    f32x4 oacc[2][2];
    #pragma unroll
    for (int qf = 0; qf < 2; qf++)
        #pragma unroll
        for (int m = 0; m < 2; m++)
            oacc[qf][m] = (f32x4){0.f, 0.f, 0.f, 0.f};
    float mrun[2] = {-INFINITY, -INFINITY};
    float lrun[2] = {0.f, 0.f};

    const f16* khb = kbuf + ((size_t)(b * NS)) * DIMC + hh * HDIM + 8 * g;
    const f16* vhb = vthi + ((size_t)(bh * HDIM)) * NS + 8 * g;
    const f16* vlb = vtlo + ((size_t)(bh * HDIM)) * NS + 8 * g;
    const float* cfb = conf + b * NS + 4 * g;

    int addr0 = (s + ((g & 1) << 5)) << 2;   // src lane s + 32*(g&1), bytes
    int addr1 = addr0 + 64;                  // +16 lanes
    bool hiHalf = (g >= 2);                  // source frag = g>>1

    for (int k0 = 0; k0 < NS; k0 += 64) {    // 64-key batch = 2 sub-chunks
        // K fragments: kh[c][f] = K[k0+32c+16f+s][d=8g+j]
        f16x8 kh[2][2];
        #pragma unroll
        for (int c = 0; c < 2; c++)
            #pragma unroll
            for (int f = 0; f < 2; f++)
                kh[c][f] = *(const f16x8*)(khb + ((size_t)(k0 + 32 * c + 16 * f + s)) * DIMC);
        // V^T fragments: vh[c][m] = Vt[16m+s][k0+32c+8g+j]
        f16x8 vh[2][2], vl[2][2];
        #pragma unroll
        for (int c = 0; c < 2; c++)
            #pragma unroll
            for (int m = 0; m < 2; m++) {
                size_t off = ((size_t)(16 * m + s)) * NS + k0 + 32 * c;
                vh[c][m] = *(const f16x8*)(vhb + off);
                vl[c][m] = *(const f16x8*)(vlb + off);
            }
        // conf: keys k0 + 32c + 16f + 4g + r
        float4 cq[2][2];
        #pragma unroll
        for (int c = 0; c < 2; c++)
            #pragma unroll
            for (int f = 0; f < 2; f++)
                cq[c][f] = *(const float4*)(cfb + k0 + 32 * c + 16 * f);

        #pragma unroll
        for (int qf = 0; qf < 2; qf++) {
            // S^T = K * Q^T: 4 independent fp16 products
            f32x4 sa[2][2];
            #pragma unroll
            for (int c = 0; c < 2; c++)
                #pragma unroll
                for (int f = 0; f < 2; f++) {
                    f32x4 z = (f32x4){0.f, 0.f, 0.f, 0.f};
                    sa[c][f] = MFMA16F(kh[c][f], qh[qf], z);
                }
            // scores + max over 16 slots
            float sc[2][2][4], mc = -INFINITY;
            #pragma unroll
            for (int c = 0; c < 2; c++)
                #pragma unroll
                for (int f = 0; f < 2; f++) {
                    const float* cp = &cq[c][f].x;
                    #pragma unroll
                    for (int r = 0; r < 4; r++) {
                        sc[c][f][r] = sa[c][f][r] * SCALE_ATTN + cp[r];
                        mc = fmaxf(mc, sc[c][f][r]);
                    }
                }
            mc = fmaxf(mc, __shfl_xor(mc, 16));
            mc = fmaxf(mc, __shfl_xor(mc, 32));
            if (__any(mc > mrun[qf])) {          // exact skip: corr==1 otherwise
                float mnew = fmaxf(mrun[qf], mc);
                float corr = __expf(mrun[qf] - mnew);  // exp(-inf)=0 first iter
                mrun[qf] = mnew;
                lrun[qf] *= corr;
                #pragma unroll
                for (int m = 0; m < 2; m++)
                    #pragma unroll
                    for (int r = 0; r < 4; r++)
                        oacc[qf][m][r] *= corr;
            }
            float p[2][2][4], ls = 0.f;
            #pragma unroll
            for (int c = 0; c < 2; c++)
                #pragma unroll
                for (int f = 0; f < 2; f++)
                    #pragma unroll
                    for (int r = 0; r < 4; r++) {
                        p[c][f][r] = __expf(sc[c][f][r] - mrun[qf]);
                        ls += p[c][f][r];
                    }
            ls += __shfl_xor(ls, 16);
            ls += __shfl_xor(ls, 32);
            lrun[qf] += ls;

            // P -> fp16 packed words; gather to PV B-operand per sub-chunk
            #pragma unroll
            for (int c = 0; c < 2; c++) {
                unsigned w00 = __builtin_bit_cast(unsigned,
                    __builtin_amdgcn_cvt_pkrtz(p[c][0][0], p[c][0][1]));
                unsigned w01 = __builtin_bit_cast(unsigned,
                    __builtin_amdgcn_cvt_pkrtz(p[c][0][2], p[c][0][3]));
                unsigned w10 = __builtin_bit_cast(unsigned,
                    __builtin_amdgcn_cvt_pkrtz(p[c][1][0], p[c][1][1]));
                unsigned w11 = __builtin_bit_cast(unsigned,
                    __builtin_amdgcn_cvt_pkrtz(p[c][1][2], p[c][1][3]));
                unsigned bw[4];
                {
                    int a0  = __builtin_amdgcn_ds_bpermute(addr0, (int)w00);
                    int a0h = __builtin_amdgcn_ds_bpermute(addr0, (int)w10);
                    bw[0] = (unsigned)(hiHalf ? a0h : a0);
                    int a1  = __builtin_amdgcn_ds_bpermute(addr0, (int)w01);
                    int a1h = __builtin_amdgcn_ds_bpermute(addr0, (int)w11);
                    bw[1] = (unsigned)(hiHalf ? a1h : a1);
                    int a2  = __builtin_amdgcn_ds_bpermute(addr1, (int)w00);
                    int a2h = __builtin_amdgcn_ds_bpermute(addr1, (int)w10);
                    bw[2] = (unsigned)(hiHalf ? a2h : a2);
                    int a3  = __builtin_amdgcn_ds_bpermute(addr1, (int)w01);
                    int a3h = __builtin_amdgcn_ds_bpermute(addr1, (int)w11);
                    bw[3] = (unsigned)(hiHalf ? a3h : a3);
                }
                union { unsigned u[4]; f16x8 v; } Bv;
                #pragma unroll
                for (int j = 0; j < 4; j++) Bv.u[j] = bw[j];
                // O^T += V^T * P^T (Vhi + Vlo products)
                #pragma unroll
                for (int m = 0; m < 2; m++) {
                    oacc[qf][m] = MFMA16F(vh[c][m], Bv.v, oacc[qf][m]);
                    oacc[qf][m] = MFMA16F(vl[c][m], Bv.v, oacc[qf][m]);
                }
            }
        } // qf
    } // 64-key batch

    // epilogue: oacc[qf][m][r] = O^T[d=16m+4g+r][q=q0+16qf+s]; f16 out
    #pragma unroll
    for (int qf = 0; qf < 2; qf++) {
        float invl = 1.f / lrun[qf];
        f16* orow = abuf + ((size_t)(b * NQ + q0 + qf * 16 + s)) * DIMC + hh * HDIM;
        #pragma unroll
        for (int m = 0; m < 2; m++) {
            f16x4 o;
            #pragma unroll
            for (int r = 0; r < 4; r++) o[r] = (f16)(oacc[qf][m][r] * invl);
            *(f16x4*)(orow + 16 * m + 4 * g) = o;
        }
    }
}

extern "C" void kernel_launch(void* const* d_in, const int* in_sizes, int n_in,
                              void* d_out, int out_size, void* d_ws, size_t ws_size,
                              hipStream_t stream)
{
    (void)in_sizes; (void)n_in; (void)out_size; (void)ws_size;
    const float* x    = (const float*)d_in[0];
    const float* xsrc = (const float*)d_in[1];
    const float* loc  = (const float*)d_in[2];
    const float* csrc = (const float*)d_in[3];
    const float* Wq   = (const float*)d_in[4];
    const float* Wk   = (const float*)d_in[5];
    const float* Wv   = (const float*)d_in[6];
    const float* Wsr  = (const float*)d_in[7];
    const float* bsr  = (const float*)d_in[8];
    const float* lng  = (const float*)d_in[9];
    const float* lnb  = (const float*)d_in[10];
    const float* Wp   = (const float*)d_in[11];
    const float* bp   = (const float*)d_in[12];
    // d_in[13]=H(64), d_in[14]=W(64): fixed by setup_inputs; h=w=32 hardcoded.

    const int MS = BATCH * NS * DIMC;     // 1,048,576
    const int MQ = BATCH * NQ * DIMC;     // 4,194,304
    const int WSZ = DIMC * DIMC;          // 65,536

    float* ws      = (float*)d_ws;
    float* feat    = ws;                  // MS f32
    float* xs      = feat + MS;           // MS f32
    float* cnt     = xs + MS;             // 4096
    float* confsum = cnt + BATCH * NS;    // 4096
    float* conf    = confsum + BATCH * NS;// 4096
    f16* q16    = (f16*)(conf + BATCH * NS);  // MQ f16
    f16* k16    = q16 + MQ;               // MS f16
    f16* vthi16 = k16 + MS;               // MS f16
    f16* vtlo16 = vthi16 + MS;            // MS f16
    f16* abuf16 = vtlo16 + MS;            // MQ f16
    unsigned short* wsrh = (unsigned short*)(abuf16 + MQ);  // 4 x WSZ bf16
    unsigned short* wsrl = wsrh + WSZ;
    unsigned short* wvh  = wsrl + WSZ;
    unsigned short* wvl  = wvh  + WSZ;
    f16* wq16 = (f16*)(wvl + WSZ);        // 3 x WSZ f16
    f16* wk16 = wq16 + WSZ;
    f16* wp16 = wk16 + WSZ;               // total ~31 MB
    float* outp = (float*)d_out;

    hipMemsetAsync(feat, 0, (size_t)MS * sizeof(float), stream);
    hipMemsetAsync(cnt, 0, (size_t)(2 * BATCH * NS) * sizeof(float), stream);

    wprep_kernel<<<dim3(64, 5), 256, 0, stream>>>(
        Wsr, Wv, Wq, Wk, Wp, wsrh, wsrl, wvh, wvl, wq16, wk16, wp16);
    scatter_kernel<<<BATCH * NQ, DIMC, 0, stream>>>(xsrc, loc, csrc, feat, cnt, confsum);
    featfin_kernel<<<BATCH * NS, DIMC, 0, stream>>>(cnt, confsum, feat, conf);
    mfma_gemm_kernel<0, true ><<<dim3(BATCH * NS / 64, 2), 256, 0, stream>>>(
        feat, wsrh, wsrl, bsr, xs, nullptr, nullptr);
    ln_kernel<<<BATCH * NS, DIMC, 0, stream>>>(xs, lng, lnb);
    gemm16_kernel<false, true, false><<<dim3(BATCH * NS / 64, 2), 256, 0, stream>>>(
        xs, wk16, nullptr, nullptr, k16);
    mfma_gemm_kernel<2, false><<<dim3(BATCH * NS / 64, 2), 256, 0, stream>>>(
        xs, wvh, wvl, nullptr, nullptr, vthi16, vtlo16);
    gemm16_kernel<false, true, false><<<dim3(BATCH * NQ / 64, 2), 256, 0, stream>>>(
        x, wq16, nullptr, nullptr, q16);
    attn_mfma_kernel<<<BATCH * NHEADS * (NQ / 128), 256, 0, stream>>>(
        q16, k16, vthi16, vtlo16, conf, abuf16);
    gemm16_kernel<true, false, true><<<dim3(BATCH * NQ / 64, 2), 256, 0, stream>>>(
        abuf16, wp16, bp, outp, nullptr);
}

// Round 8
// 231.800 us; speedup vs baseline: 1.3865x; 1.0933x over previous
//
#include <hip/hip_runtime.h>
#include <math.h>

#define DIMC   256
#define NQ     4096
#define BATCH  4
#define NS     1024    // (H/SR)*(W/SR) = 32*32
#define WG     32
#define HG     32
#define NHEADS 8
#define HDIM   32
#define SCALE_ATTN 0.17677669529663687f  // 32^-0.5

typedef _Float16 f16;
typedef __attribute__((ext_vector_type(8))) __bf16    bf16x8;
typedef __attribute__((ext_vector_type(8))) _Float16  f16x8;
typedef __attribute__((ext_vector_type(4))) _Float16  f16x4;
typedef __attribute__((ext_vector_type(4))) float     f32x4;

#define MFMA16B(A, B, C)  __builtin_amdgcn_mfma_f32_16x16x32_bf16((A), (B), (C), 0, 0, 0)
#define MFMA16F(A, B, C)  __builtin_amdgcn_mfma_f32_16x16x32_f16((A), (B), (C), 0, 0, 0)
#define MFMA16K16(A, B, C) __builtin_amdgcn_mfma_f32_16x16x16f16((A), (B), (C), 0, 0, 0)

static __device__ __forceinline__ unsigned short bf16_hi(float v) {
    return __builtin_bit_cast(unsigned short, (__bf16)v);
}

// ---------------- scatter: token2map segment-sum ----------------
__global__ __launch_bounds__(DIMC) void scatter_kernel(
    const float* __restrict__ xsrc, const float* __restrict__ loc,
    const float* __restrict__ csrc, float* __restrict__ feat,
    float* __restrict__ cnt, float* __restrict__ confsum)
{
    int token = blockIdx.x;          // B*NQ tokens
    int b = token >> 12;             // NQ = 4096
    int c = threadIdx.x;
    float lx = loc[token * 2 + 0];
    float ly = loc[token * 2 + 1];
    lx = fminf(fmaxf(lx, 0.f), 1.f) * (float)(WG - 1);
    ly = fminf(fmaxf(ly, 0.f), 1.f) * (float)(HG - 1);
    int ix = (int)rintf(lx);         // round-half-even, matches jnp.round
    int iy = (int)rintf(ly);
    int cell = b * NS + iy * WG + ix;
    atomicAdd(&feat[cell * DIMC + c], xsrc[token * DIMC + c]);
    if (c == 0) {
        atomicAdd(&cnt[cell], 1.f);
        atomicAdd(&confsum[cell], csrc[token]);
    }
}

// ---------------- finalize: feat /= (cnt+eps), mask; conf map ----------------
__global__ __launch_bounds__(DIMC) void featfin_kernel(
    const float* __restrict__ cnt, const float* __restrict__ confsum,
    float* __restrict__ feat, float* __restrict__ conf)
{
    int m = blockIdx.x;              // B*NS cells
    int c = threadIdx.x;
    float cv = cnt[m];
    float inv = (cv > 0.f) ? 1.f / (cv + 1e-6f) : 0.f;
    feat[m * DIMC + c] *= inv;
    if (c == 0) conf[m] = confsum[m] * inv;
}

// ---------------- weight prep: Wsr,Wv -> bf16 hi/lo; Wq,Wk,Wp -> f16 ----------------
__global__ __launch_bounds__(256) void wprep_kernel(
    const float* __restrict__ Wsr, const float* __restrict__ Wv,
    const float* __restrict__ Wq, const float* __restrict__ Wk,
    const float* __restrict__ Wp,
    unsigned short* __restrict__ wsrh, unsigned short* __restrict__ wsrl,
    unsigned short* __restrict__ wvh, unsigned short* __restrict__ wvl,
    f16* __restrict__ wq16, f16* __restrict__ wk16, f16* __restrict__ wp16)
{
    int i = (blockIdx.x * 256 + threadIdx.x) * 4;   // grid.x = 64 -> 65536 elems
    int m = blockIdx.y;
    if (m < 2) {
        const float* W = m ? Wv : Wsr;
        unsigned short* H = m ? wvh : wsrh;
        unsigned short* L = m ? wvl : wsrl;
        float4 v = *(const float4*)(W + i);
        float vv[4] = {v.x, v.y, v.z, v.w};
        ushort4 h, l;
        unsigned short* hp = &h.x; unsigned short* lp = &l.x;
        #pragma unroll
        for (int j = 0; j < 4; j++) {
            __bf16 hb = (__bf16)vv[j];
            hp[j] = __builtin_bit_cast(unsigned short, hb);
            lp[j] = bf16_hi(vv[j] - (float)hb);
        }
        *(ushort4*)(H + i) = h;
        *(ushort4*)(L + i) = l;
    } else {
        const float* W = (m == 2) ? Wq : (m == 3) ? Wk : Wp;
        f16* O = (m == 2) ? wq16 : (m == 3) ? wk16 : wp16;
        float4 v = *(const float4*)(W + i);
        f16x4 h = {(f16)v.x, (f16)v.y, (f16)v.z, (f16)v.w};
        *(f16x4*)(O + i) = h;
    }
}

// ---------------- bf16x2-split MFMA GEMM (exact-ish): Wsr, Wv ----------------
// EPI: 0 = f32 row-major; 2 = single f16 transposed (V): out[(b*256+c)*1024+key].
template <int EPI, bool HASBIAS>
__global__ __launch_bounds__(256) void mfma_gemm_kernel(
    const float* __restrict__ A,
    const unsigned short* __restrict__ Whi, const unsigned short* __restrict__ Wlo,
    const float* __restrict__ bias, float* __restrict__ outF,
    f16* __restrict__ o16a)
{
    int r0 = blockIdx.x * 64;
    int c0 = blockIdx.y * 128;
    int wave = threadIdx.x >> 6;
    int lane = threadIdx.x & 63;
    int s = lane & 15, g = lane >> 4;

    int arow = r0 + wave * 16 + s;              // A-frag row for this lane
    const float* ap = A + (size_t)arow * DIMC + 8 * g;

    f32x4 acc[8];
    #pragma unroll
    for (int cf = 0; cf < 8; cf++) {
        float bv = HASBIAS ? bias[c0 + cf * 16 + s] : 0.f;
        acc[cf] = (f32x4){bv, bv, bv, bv};
    }

    #pragma unroll
    for (int kk = 0; kk < 8; kk++) {
        float4 a0 = *(const float4*)(ap + kk * 32);
        float4 a1 = *(const float4*)(ap + kk * 32 + 4);
        float av[8] = {a0.x, a0.y, a0.z, a0.w, a1.x, a1.y, a1.z, a1.w};
        bf16x8 ah, al;
        #pragma unroll
        for (int j = 0; j < 8; j++) {
            __bf16 hb = (__bf16)av[j];
            ah[j] = hb;
            al[j] = (__bf16)(av[j] - (float)hb);
        }
        #pragma unroll
        for (int cf = 0; cf < 8; cf++) {
            size_t woff = (size_t)(c0 + cf * 16 + s) * DIMC + kk * 32 + 8 * g;
            bf16x8 bh = *(const bf16x8*)(Whi + woff);
            bf16x8 bl = *(const bf16x8*)(Wlo + woff);
            acc[cf] = MFMA16B(ah, bh, acc[cf]);
            acc[cf] = MFMA16B(al, bh, acc[cf]);
            acc[cf] = MFMA16B(ah, bl, acc[cf]);
        }
    }

    int rbase = r0 + wave * 16 + 4 * g;         // output rows rbase..rbase+3
    if (EPI == 0) {
        #pragma unroll
        for (int cf = 0; cf < 8; cf++) {
            int c = c0 + cf * 16 + s;
            #pragma unroll
            for (int r = 0; r < 4; r++)
                outF[(size_t)(rbase + r) * DIMC + c] = acc[cf][r];
        }
    } else {
        int b = rbase >> 10;                    // 64-row blocks never cross batch
        int key0 = rbase & 1023;
        #pragma unroll
        for (int cf = 0; cf < 8; cf++) {
            int c = c0 + cf * 16 + s;
            f16x4 h;
            #pragma unroll
            for (int r = 0; r < 4; r++) h[r] = (f16)acc[cf][r];
            size_t off = ((size_t)(b * DIMC + c)) * NS + key0;
            *(f16x4*)(o16a + off) = h;
        }
    }
}

// ---------------- single-product fp16 GEMM: Wq, Wk, Wp ----------------
// A16: A is f16 (else fp32, cvt in regs). OUT16: f16 out (else f32).
template <bool A16, bool OUT16, bool HASBIAS>
__global__ __launch_bounds__(256) void gemm16_kernel(
    const void* __restrict__ Ain, const f16* __restrict__ W,
    const float* __restrict__ bias, float* __restrict__ outF,
    f16* __restrict__ out16)
{
    int r0 = blockIdx.x * 64;
    int c0 = blockIdx.y * 128;
    int wave = threadIdx.x >> 6;
    int lane = threadIdx.x & 63;
    int s = lane & 15, g = lane >> 4;
    int arow = r0 + wave * 16 + s;

    f32x4 acc[8];
    #pragma unroll
    for (int cf = 0; cf < 8; cf++) {
        float bv = HASBIAS ? bias[c0 + cf * 16 + s] : 0.f;
        acc[cf] = (f32x4){bv, bv, bv, bv};
    }

    #pragma unroll
    for (int kk = 0; kk < 8; kk++) {
        f16x8 a;
        if (A16) {
            a = *(const f16x8*)((const f16*)Ain + (size_t)arow * DIMC + kk * 32 + 8 * g);
        } else {
            const float* ap = (const float*)Ain + (size_t)arow * DIMC + kk * 32 + 8 * g;
            float4 a0 = *(const float4*)ap;
            float4 a1 = *(const float4*)(ap + 4);
            a = (f16x8){(f16)a0.x, (f16)a0.y, (f16)a0.z, (f16)a0.w,
                        (f16)a1.x, (f16)a1.y, (f16)a1.z, (f16)a1.w};
        }
        #pragma unroll
        for (int cf = 0; cf < 8; cf++) {
            f16x8 bfrag = *(const f16x8*)(W + (size_t)(c0 + cf * 16 + s) * DIMC + kk * 32 + 8 * g);
            acc[cf] = MFMA16F(a, bfrag, acc[cf]);
        }
    }

    int rbase = r0 + wave * 16 + 4 * g;
    #pragma unroll
    for (int cf = 0; cf < 8; cf++) {
        int c = c0 + cf * 16 + s;
        #pragma unroll
        for (int r = 0; r < 4; r++) {
            if (OUT16) out16[(size_t)(rbase + r) * DIMC + c] = (f16)acc[cf][r];
            else       outF [(size_t)(rbase + r) * DIMC + c] = acc[cf][r];
        }
    }
}

// ---------------- layernorm in place over last dim ----------------
__global__ __launch_bounds__(DIMC) void ln_kernel(
    float* __restrict__ xs, const float* __restrict__ g, const float* __restrict__ b)
{
    int m = blockIdx.x;
    int c = threadIdx.x;
    float v = xs[(size_t)m * DIMC + c];
    float s = v, q = v * v;
    #pragma unroll
    for (int off = 32; off > 0; off >>= 1) {
        s += __shfl_xor(s, off);
        q += __shfl_xor(q, off);
    }
    __shared__ float sh1[4], sh2[4];
    int wid = c >> 6, lane = c & 63;
    if (lane == 0) { sh1[wid] = s; sh2[wid] = q; }
    __syncthreads();
    s = sh1[0] + sh1[1] + sh1[2] + sh1[3];
    q = sh2[0] + sh2[1] + sh2[2] + sh2[3];
    float mu  = s * (1.f / DIMC);
    float var = q * (1.f / DIMC) - mu * mu;
    xs[(size_t)m * DIMC + c] = (v - mu) * rsqrtf(var + 1e-5f) * g[c] + b[c];
}

// ---------------- MFMA flash attention (fp16, crossbar-free PV) ----------------
// 32 queries/wave, 32-key chunks (R5 shape). QK = 16x16x32; PV = 16x16x16 whose
// B-operand layout equals the QK C-layout -> P feeds PV with 2 cvt_pkrtz only.
// Q,K,P,V all fp16 single. Exact skip-rescale. f16 output.
__global__ __launch_bounds__(256) void attn_mfma_kernel(
    const f16* __restrict__ qbuf, const f16* __restrict__ kbuf,
    const f16* __restrict__ vt16, const float* __restrict__ conf,
    f16* __restrict__ abuf)
{
    int blk  = blockIdx.x;            // B*H*(NQ/128) = 1024
    int qt   = blk & 31;              // NQ/128 = 32
    int bh   = blk >> 5;
    int hh   = bh & (NHEADS - 1);
    int b    = bh >> 3;
    int wave = threadIdx.x >> 6;
    int lane = threadIdx.x & 63;
    int s = lane & 15, g = lane >> 4;
    int q0 = qt * 128 + wave * 32;

    // Q fragments (B-operand for S^T): lane holds Q[q0+qf*16+s][d=8g+j]
    f16x8 qh[2];
    #pragma unroll
    for (int qf = 0; qf < 2; qf++)
        qh[qf] = *(const f16x8*)(qbuf +
            ((size_t)(b * NQ + q0 + qf * 16 + s)) * DIMC + hh * HDIM + 8 * g);

    f32x4 oacc[2][2];
    #pragma unroll
    for (int qf = 0; qf < 2; qf++)
        #pragma unroll
        for (int m = 0; m < 2; m++)
            oacc[qf][m] = (f32x4){0.f, 0.f, 0.f, 0.f};
    float mrun[2] = {-INFINITY, -INFINITY};
    float lrun[2] = {0.f, 0.f};

    const f16* khb = kbuf + ((size_t)(b * NS)) * DIMC + hh * HDIM + 8 * g;
    const f16* vtb = vt16 + ((size_t)(bh * HDIM)) * NS;   // rows d, cols key
    const float* cfb = conf + b * NS + 4 * g;

    for (int k0 = 0; k0 < NS; k0 += 32) {
        // K fragments (A-operand 16x16x32): lane holds K[k0+16f+s][d=8g+j]
        f16x8 kh[2];
        #pragma unroll
        for (int f = 0; f < 2; f++)
            kh[f] = *(const f16x8*)(khb + ((size_t)(k0 + 16 * f + s)) * DIMC);
        // V^T fragments (A-operand 16x16x16): vt[f][m] = Vt[16m+s][k0+16f+4g+j], j=0..3
        f16x4 vt[2][2];
        #pragma unroll
        for (int f = 0; f < 2; f++)
            #pragma unroll
            for (int m = 0; m < 2; m++)
                vt[f][m] = *(const f16x4*)(vtb + ((size_t)(16 * m + s)) * NS
                                               + k0 + 16 * f + 4 * g);
        // conf for this lane's score slots: keys k0 + 16f + 4g + r
        float4 cq[2];
        #pragma unroll
        for (int f = 0; f < 2; f++)
            cq[f] = *(const float4*)(cfb + k0 + 16 * f);

        #pragma unroll
        for (int qf = 0; qf < 2; qf++) {
            // S^T = K * Q^T (single fp16 product per 16-key frag)
            f32x4 sa[2];
            #pragma unroll
            for (int f = 0; f < 2; f++) {
                f32x4 z = (f32x4){0.f, 0.f, 0.f, 0.f};
                sa[f] = MFMA16F(kh[f], qh[qf], z);
            }
            float sc[2][4], mc = -INFINITY;
            #pragma unroll
            for (int f = 0; f < 2; f++) {
                const float* cp = &cq[f].x;
                #pragma unroll
                for (int r = 0; r < 4; r++) {
                    sc[f][r] = sa[f][r] * SCALE_ATTN + cp[r];
                    mc = fmaxf(mc, sc[f][r]);
                }
            }
            mc = fmaxf(mc, __shfl_xor(mc, 16));
            mc = fmaxf(mc, __shfl_xor(mc, 32));
            if (__any(mc > mrun[qf])) {          // exact skip: corr==1 otherwise
                float mnew = fmaxf(mrun[qf], mc);
                float corr = __expf(mrun[qf] - mnew);  // exp(-inf)=0 first chunk
                mrun[qf] = mnew;
                lrun[qf] *= corr;
                #pragma unroll
                for (int m = 0; m < 2; m++)
                    #pragma unroll
                    for (int r = 0; r < 4; r++)
                        oacc[qf][m][r] *= corr;
            }
            float p[2][4], ls = 0.f;
            #pragma unroll
            for (int f = 0; f < 2; f++)
                #pragma unroll
                for (int r = 0; r < 4; r++) {
                    p[f][r] = __expf(sc[f][r] - mrun[qf]);
                    ls += p[f][r];
                }
            ls += __shfl_xor(ls, 16);
            ls += __shfl_xor(ls, 32);
            lrun[qf] += ls;

            // P -> B-operand of 16x16x16 directly: lane already holds keys 4g+r.
            #pragma unroll
            for (int f = 0; f < 2; f++) {
                union { unsigned u[2]; f16x4 v; } Bp;
                Bp.u[0] = __builtin_bit_cast(unsigned,
                    __builtin_amdgcn_cvt_pkrtz(p[f][0], p[f][1]));
                Bp.u[1] = __builtin_bit_cast(unsigned,
                    __builtin_amdgcn_cvt_pkrtz(p[f][2], p[f][3]));
                // O^T += Vt * P^T over this 16-key slice
                #pragma unroll
                for (int m = 0; m < 2; m++)
                    oacc[qf][m] = MFMA16K16(vt[f][m], Bp.v, oacc[qf][m]);
            }
        } // qf
    } // chunk

    // epilogue: oacc[qf][m][r] = O^T[d=16m+4g+r][q=q0+16qf+s]; f16 out
    #pragma unroll
    for (int qf = 0; qf < 2; qf++) {
        float invl = 1.f / lrun[qf];
        f16* orow = abuf + ((size_t)(b * NQ + q0 + qf * 16 + s)) * DIMC + hh * HDIM;
        #pragma unroll
        for (int m = 0; m < 2; m++) {
            f16x4 o;
            #pragma unroll
            for (int r = 0; r < 4; r++) o[r] = (f16)(oacc[qf][m][r] * invl);
            *(f16x4*)(orow + 16 * m + 4 * g) = o;
        }
    }
}

extern "C" void kernel_launch(void* const* d_in, const int* in_sizes, int n_in,
                              void* d_out, int out_size, void* d_ws, size_t ws_size,
                              hipStream_t stream)
{
    (void)in_sizes; (void)n_in; (void)out_size; (void)ws_size;
    const float* x    = (const float*)d_in[0];
    const float* xsrc = (const float*)d_in[1];
    const float* loc  = (const float*)d_in[2];
    const float* csrc = (const float*)d_in[3];
    const float* Wq   = (const float*)d_in[4];
    const float* Wk   = (const float*)d_in[5];
    const float* Wv   = (const float*)d_in[6];
    const float* Wsr  = (const float*)d_in[7];
    const float* bsr  = (const float*)d_in[8];
    const float* lng  = (const float*)d_in[9];
    const float* lnb  = (const float*)d_in[10];
    const float* Wp   = (const float*)d_in[11];
    const float* bp   = (const float*)d_in[12];
    // d_in[13]=H(64), d_in[14]=W(64): fixed by setup_inputs; h=w=32 hardcoded.

    const int MS = BATCH * NS * DIMC;     // 1,048,576
    const int MQ = BATCH * NQ * DIMC;     // 4,194,304
    const int WSZ = DIMC * DIMC;          // 65,536

    float* ws      = (float*)d_ws;
    float* feat    = ws;                  // MS f32
    float* xs      = feat + MS;           // MS f32
    float* cnt     = xs + MS;             // 4096
    float* confsum = cnt + BATCH * NS;    // 4096
    float* conf    = confsum + BATCH * NS;// 4096
    f16* q16    = (f16*)(conf + BATCH * NS);  // MQ f16
    f16* k16    = q16 + MQ;               // MS f16
    f16* vt16   = k16 + MS;               // MS f16 (single, transposed)
    f16* abuf16 = vt16 + MS;              // MQ f16
    unsigned short* wsrh = (unsigned short*)(abuf16 + MQ);  // 4 x WSZ bf16
    unsigned short* wsrl = wsrh + WSZ;
    unsigned short* wvh  = wsrl + WSZ;
    unsigned short* wvl  = wvh  + WSZ;
    f16* wq16 = (f16*)(wvl + WSZ);        // 3 x WSZ f16
    f16* wk16 = wq16 + WSZ;
    f16* wp16 = wk16 + WSZ;               // total ~29 MB
    float* outp = (float*)d_out;

    hipMemsetAsync(feat, 0, (size_t)MS * sizeof(float), stream);
    hipMemsetAsync(cnt, 0, (size_t)(2 * BATCH * NS) * sizeof(float), stream);

    wprep_kernel<<<dim3(64, 5), 256, 0, stream>>>(
        Wsr, Wv, Wq, Wk, Wp, wsrh, wsrl, wvh, wvl, wq16, wk16, wp16);
    scatter_kernel<<<BATCH * NQ, DIMC, 0, stream>>>(xsrc, loc, csrc, feat, cnt, confsum);
    featfin_kernel<<<BATCH * NS, DIMC, 0, stream>>>(cnt, confsum, feat, conf);
    mfma_gemm_kernel<0, true ><<<dim3(BATCH * NS / 64, 2), 256, 0, stream>>>(
        feat, wsrh, wsrl, bsr, xs, nullptr);
    ln_kernel<<<BATCH * NS, DIMC, 0, stream>>>(xs, lng, lnb);
    gemm16_kernel<false, true, false><<<dim3(BATCH * NS / 64, 2), 256, 0, stream>>>(
        xs, wk16, nullptr, nullptr, k16);
    mfma_gemm_kernel<2, false><<<dim3(BATCH * NS / 64, 2), 256, 0, stream>>>(
        xs, wvh, wvl, nullptr, nullptr, vt16);
    gemm16_kernel<false, true, false><<<dim3(BATCH * NQ / 64, 2), 256, 0, stream>>>(
        x, wq16, nullptr, nullptr, q16);
    attn_mfma_kernel<<<BATCH * NHEADS * (NQ / 128), 256, 0, stream>>>(
        q16, k16, vt16, conf, abuf16);
    gemm16_kernel<true, false, true><<<dim3(BATCH * NQ / 64, 2), 256, 0, stream>>>(
        abuf16, wp16, bp, outp, nullptr);
}

// Round 9
// 229.979 us; speedup vs baseline: 1.3974x; 1.0079x over previous
//
#include <hip/hip_runtime.h>
#include <math.h>

#define DIMC   256
#define NQ     4096
#define BATCH  4
#define NS     1024    // (H/SR)*(W/SR) = 32*32
#define WG     32
#define HG     32
#define NHEADS 8
#define HDIM   32
#define NSPLIT 2
#define SCALE_ATTN 0.17677669529663687f  // 32^-0.5

typedef _Float16 f16;
typedef __attribute__((ext_vector_type(8))) __bf16    bf16x8;
typedef __attribute__((ext_vector_type(8))) _Float16  f16x8;
typedef __attribute__((ext_vector_type(4))) _Float16  f16x4;
typedef __attribute__((ext_vector_type(4))) float     f32x4;

#define MFMA16B(A, B, C)  __builtin_amdgcn_mfma_f32_16x16x32_bf16((A), (B), (C), 0, 0, 0)
#define MFMA16F(A, B, C)  __builtin_amdgcn_mfma_f32_16x16x32_f16((A), (B), (C), 0, 0, 0)
#define MFMA16K16(A, B, C) __builtin_amdgcn_mfma_f32_16x16x16f16((A), (B), (C), 0, 0, 0)

static __device__ __forceinline__ unsigned short bf16_hi(float v) {
    return __builtin_bit_cast(unsigned short, (__bf16)v);
}

// ---------------- scatter: token2map segment-sum ----------------
__global__ __launch_bounds__(DIMC) void scatter_kernel(
    const float* __restrict__ xsrc, const float* __restrict__ loc,
    const float* __restrict__ csrc, float* __restrict__ feat,
    float* __restrict__ cnt, float* __restrict__ confsum)
{
    int token = blockIdx.x;          // B*NQ tokens
    int b = token >> 12;             // NQ = 4096
    int c = threadIdx.x;
    float lx = loc[token * 2 + 0];
    float ly = loc[token * 2 + 1];
    lx = fminf(fmaxf(lx, 0.f), 1.f) * (float)(WG - 1);
    ly = fminf(fmaxf(ly, 0.f), 1.f) * (float)(HG - 1);
    int ix = (int)rintf(lx);         // round-half-even, matches jnp.round
    int iy = (int)rintf(ly);
    int cell = b * NS + iy * WG + ix;
    atomicAdd(&feat[cell * DIMC + c], xsrc[token * DIMC + c]);
    if (c == 0) {
        atomicAdd(&cnt[cell], 1.f);
        atomicAdd(&confsum[cell], csrc[token]);
    }
}

// ---------------- finalize: feat /= (cnt+eps), mask; conf map ----------------
__global__ __launch_bounds__(DIMC) void featfin_kernel(
    const float* __restrict__ cnt, const float* __restrict__ confsum,
    float* __restrict__ feat, float* __restrict__ conf)
{
    int m = blockIdx.x;              // B*NS cells
    int c = threadIdx.x;
    float cv = cnt[m];
    float inv = (cv > 0.f) ? 1.f / (cv + 1e-6f) : 0.f;
    feat[m * DIMC + c] *= inv;
    if (c == 0) conf[m] = confsum[m] * inv;
}

// ---------------- weight prep: Wsr,Wv -> bf16 hi/lo; Wq,Wk,Wp -> f16 ----------------
__global__ __launch_bounds__(256) void wprep_kernel(
    const float* __restrict__ Wsr, const float* __restrict__ Wv,
    const float* __restrict__ Wq, const float* __restrict__ Wk,
    const float* __restrict__ Wp,
    unsigned short* __restrict__ wsrh, unsigned short* __restrict__ wsrl,
    unsigned short* __restrict__ wvh, unsigned short* __restrict__ wvl,
    f16* __restrict__ wq16, f16* __restrict__ wk16, f16* __restrict__ wp16)
{
    int i = (blockIdx.x * 256 + threadIdx.x) * 4;   // grid.x = 64 -> 65536 elems
    int m = blockIdx.y;
    if (m < 2) {
        const float* W = m ? Wv : Wsr;
        unsigned short* H = m ? wvh : wsrh;
        unsigned short* L = m ? wvl : wsrl;
        float4 v = *(const float4*)(W + i);
        float vv[4] = {v.x, v.y, v.z, v.w};
        ushort4 h, l;
        unsigned short* hp = &h.x; unsigned short* lp = &l.x;
        #pragma unroll
        for (int j = 0; j < 4; j++) {
            __bf16 hb = (__bf16)vv[j];
            hp[j] = __builtin_bit_cast(unsigned short, hb);
            lp[j] = bf16_hi(vv[j] - (float)hb);
        }
        *(ushort4*)(H + i) = h;
        *(ushort4*)(L + i) = l;
    } else {
        const float* W = (m == 2) ? Wq : (m == 3) ? Wk : Wp;
        f16* O = (m == 2) ? wq16 : (m == 3) ? wk16 : wp16;
        float4 v = *(const float4*)(W + i);
        f16x4 h = {(f16)v.x, (f16)v.y, (f16)v.z, (f16)v.w};
        *(f16x4*)(O + i) = h;
    }
}

// ---------------- bf16x2-split MFMA GEMM (exact-ish): Wsr, Wv ----------------
// NCF = col-frags per wave; rows/block = 64/(8/NCF). EPI: 0 = f32 row-major;
// 2 = single f16 transposed (V): out[(b*256+c)*1024+key].
template <int NCF, int EPI, bool HASBIAS>
__global__ __launch_bounds__(256) void mfma_gemm_kernel(
    const float* __restrict__ A,
    const unsigned short* __restrict__ Whi, const unsigned short* __restrict__ Wlo,
    const float* __restrict__ bias, float* __restrict__ outF,
    f16* __restrict__ o16a)
{
    constexpr int WPS = 8 / NCF;              // col-waves per 16-row strip
    constexpr int RB  = 64 / WPS;             // rows per block
    int r0 = blockIdx.x * RB;
    int c0 = blockIdx.y * 128;
    int wave = threadIdx.x >> 6;
    int lane = threadIdx.x & 63;
    int s = lane & 15, g = lane >> 4;
    int strip = wave / WPS, cg = wave % WPS;
    int arow = r0 + strip * 16 + s;
    int cb = c0 + cg * NCF * 16;
    const float* ap = A + (size_t)arow * DIMC + 8 * g;

    f32x4 acc[NCF];
    #pragma unroll
    for (int cf = 0; cf < NCF; cf++) {
        float bv = HASBIAS ? bias[cb + cf * 16 + s] : 0.f;
        acc[cf] = (f32x4){bv, bv, bv, bv};
    }

    #pragma unroll
    for (int kk = 0; kk < 8; kk++) {
        float4 a0 = *(const float4*)(ap + kk * 32);
        float4 a1 = *(const float4*)(ap + kk * 32 + 4);
        float av[8] = {a0.x, a0.y, a0.z, a0.w, a1.x, a1.y, a1.z, a1.w};
        bf16x8 ah, al;
        #pragma unroll
        for (int j = 0; j < 8; j++) {
            __bf16 hb = (__bf16)av[j];
            ah[j] = hb;
            al[j] = (__bf16)(av[j] - (float)hb);
        }
        #pragma unroll
        for (int cf = 0; cf < NCF; cf++) {
            size_t woff = (size_t)(cb + cf * 16 + s) * DIMC + kk * 32 + 8 * g;
            bf16x8 bh = *(const bf16x8*)(Whi + woff);
            bf16x8 bl = *(const bf16x8*)(Wlo + woff);
            acc[cf] = MFMA16B(ah, bh, acc[cf]);
            acc[cf] = MFMA16B(al, bh, acc[cf]);
            acc[cf] = MFMA16B(ah, bl, acc[cf]);
        }
    }

    int rbase = r0 + strip * 16 + 4 * g;      // output rows rbase..rbase+3
    if (EPI == 0) {
        #pragma unroll
        for (int cf = 0; cf < NCF; cf++) {
            int c = cb + cf * 16 + s;
            #pragma unroll
            for (int r = 0; r < 4; r++)
                outF[(size_t)(rbase + r) * DIMC + c] = acc[cf][r];
        }
    } else {
        int b = rbase >> 10;                  // row blocks never cross batch
        int key0 = rbase & 1023;
        #pragma unroll
        for (int cf = 0; cf < NCF; cf++) {
            int c = cb + cf * 16 + s;
            f16x4 h;
            #pragma unroll
            for (int r = 0; r < 4; r++) h[r] = (f16)acc[cf][r];
            size_t off = ((size_t)(b * DIMC + c)) * NS + key0;
            *(f16x4*)(o16a + off) = h;
        }
    }
}

// ---------------- single-product fp16 GEMM: Wq, Wk, Wp ----------------
// NCF as above. A16: A is f16. OUT16: f16 out.
template <int NCF, bool A16, bool OUT16, bool HASBIAS>
__global__ __launch_bounds__(256) void gemm16_kernel(
    const void* __restrict__ Ain, const f16* __restrict__ W,
    const float* __restrict__ bias, float* __restrict__ outF,
    f16* __restrict__ out16)
{
    constexpr int WPS = 8 / NCF;
    constexpr int RB  = 64 / WPS;
    int r0 = blockIdx.x * RB;
    int c0 = blockIdx.y * 128;
    int wave = threadIdx.x >> 6;
    int lane = threadIdx.x & 63;
    int s = lane & 15, g = lane >> 4;
    int strip = wave / WPS, cg = wave % WPS;
    int arow = r0 + strip * 16 + s;
    int cb = c0 + cg * NCF * 16;

    f32x4 acc[NCF];
    #pragma unroll
    for (int cf = 0; cf < NCF; cf++) {
        float bv = HASBIAS ? bias[cb + cf * 16 + s] : 0.f;
        acc[cf] = (f32x4){bv, bv, bv, bv};
    }

    #pragma unroll
    for (int kk = 0; kk < 8; kk++) {
        f16x8 a;
        if (A16) {
            a = *(const f16x8*)((const f16*)Ain + (size_t)arow * DIMC + kk * 32 + 8 * g);
        } else {
            const float* ap = (const float*)Ain + (size_t)arow * DIMC + kk * 32 + 8 * g;
            float4 a0 = *(const float4*)ap;
            float4 a1 = *(const float4*)(ap + 4);
            a = (f16x8){(f16)a0.x, (f16)a0.y, (f16)a0.z, (f16)a0.w,
                        (f16)a1.x, (f16)a1.y, (f16)a1.z, (f16)a1.w};
        }
        #pragma unroll
        for (int cf = 0; cf < NCF; cf++) {
            f16x8 bfrag = *(const f16x8*)(W + (size_t)(cb + cf * 16 + s) * DIMC + kk * 32 + 8 * g);
            acc[cf] = MFMA16F(a, bfrag, acc[cf]);
        }
    }

    int rbase = r0 + strip * 16 + 4 * g;
    #pragma unroll
    for (int cf = 0; cf < NCF; cf++) {
        int c = cb + cf * 16 + s;
        #pragma unroll
        for (int r = 0; r < 4; r++) {
            if (OUT16) out16[(size_t)(rbase + r) * DIMC + c] = (f16)acc[cf][r];
            else       outF [(size_t)(rbase + r) * DIMC + c] = acc[cf][r];
        }
    }
}

// ---------------- layernorm in place over last dim ----------------
__global__ __launch_bounds__(DIMC) void ln_kernel(
    float* __restrict__ xs, const float* __restrict__ g, const float* __restrict__ b)
{
    int m = blockIdx.x;
    int c = threadIdx.x;
    float v = xs[(size_t)m * DIMC + c];
    float s = v, q = v * v;
    #pragma unroll
    for (int off = 32; off > 0; off >>= 1) {
        s += __shfl_xor(s, off);
        q += __shfl_xor(q, off);
    }
    __shared__ float sh1[4], sh2[4];
    int wid = c >> 6, lane = c & 63;
    if (lane == 0) { sh1[wid] = s; sh2[wid] = q; }
    __syncthreads();
    s = sh1[0] + sh1[1] + sh1[2] + sh1[3];
    q = sh2[0] + sh2[1] + sh2[2] + sh2[3];
    float mu  = s * (1.f / DIMC);
    float var = q * (1.f / DIMC) - mu * mu;
    xs[(size_t)m * DIMC + c] = (v - mu) * rsqrtf(var + 1e-5f) * g[c] + b[c];
}

// ---------------- MFMA flash attention, K-split (fp16, crossbar-free PV) ----------------
// Identical per-wave structure to R8; each block handles 512 keys. Writes
// per-split normalized O (f16) and (m,l) per query.
__global__ __launch_bounds__(256) void attn_mfma_kernel(
    const f16* __restrict__ qbuf, const f16* __restrict__ kbuf,
    const f16* __restrict__ vt16, const float* __restrict__ conf,
    f16* __restrict__ opart, float2* __restrict__ ml)
{
    int blk  = blockIdx.x;            // [split][bh][qt] = 2*32*32 = 2048
    int qt   = blk & 31;              // NQ/128 = 32
    int bh   = (blk >> 5) & 31;
    int split = blk >> 10;
    int hh   = bh & (NHEADS - 1);
    int b    = bh >> 3;
    int wave = threadIdx.x >> 6;
    int lane = threadIdx.x & 63;
    int s = lane & 15, g = lane >> 4;
    int q0 = qt * 128 + wave * 32;

    // Q fragments (B-operand for S^T): lane holds Q[q0+qf*16+s][d=8g+j]
    f16x8 qh[2];
    #pragma unroll
    for (int qf = 0; qf < 2; qf++)
        qh[qf] = *(const f16x8*)(qbuf +
            ((size_t)(b * NQ + q0 + qf * 16 + s)) * DIMC + hh * HDIM + 8 * g);

    f32x4 oacc[2][2];
    #pragma unroll
    for (int qf = 0; qf < 2; qf++)
        #pragma unroll
        for (int m = 0; m < 2; m++)
            oacc[qf][m] = (f32x4){0.f, 0.f, 0.f, 0.f};
    float mrun[2] = {-INFINITY, -INFINITY};
    float lrun[2] = {0.f, 0.f};

    const f16* khb = kbuf + ((size_t)(b * NS)) * DIMC + hh * HDIM + 8 * g;
    const f16* vtb = vt16 + ((size_t)(bh * HDIM)) * NS;   // rows d, cols key
    const float* cfb = conf + b * NS + 4 * g;

    int k_begin = split * (NS / NSPLIT);
    int k_end   = k_begin + (NS / NSPLIT);
    for (int k0 = k_begin; k0 < k_end; k0 += 32) {
        // K fragments (A-operand 16x16x32): lane holds K[k0+16f+s][d=8g+j]
        f16x8 kh[2];
        #pragma unroll
        for (int f = 0; f < 2; f++)
            kh[f] = *(const f16x8*)(khb + ((size_t)(k0 + 16 * f + s)) * DIMC);
        // V^T fragments (A-operand 16x16x16): vt[f][m] = Vt[16m+s][k0+16f+4g+j]
        f16x4 vt[2][2];
        #pragma unroll
        for (int f = 0; f < 2; f++)
            #pragma unroll
            for (int m = 0; m < 2; m++)
                vt[f][m] = *(const f16x4*)(vtb + ((size_t)(16 * m + s)) * NS
                                               + k0 + 16 * f + 4 * g);
        // conf for this lane's score slots: keys k0 + 16f + 4g + r
        float4 cq[2];
        #pragma unroll
        for (int f = 0; f < 2; f++)
            cq[f] = *(const float4*)(cfb + k0 + 16 * f);

        #pragma unroll
        for (int qf = 0; qf < 2; qf++) {
            // S^T = K * Q^T (single fp16 product per 16-key frag)
            f32x4 sa[2];
            #pragma unroll
            for (int f = 0; f < 2; f++) {
                f32x4 z = (f32x4){0.f, 0.f, 0.f, 0.f};
                sa[f] = MFMA16F(kh[f], qh[qf], z);
            }
            float sc[2][4], mc = -INFINITY;
            #pragma unroll
            for (int f = 0; f < 2; f++) {
                const float* cp = &cq[f].x;
                #pragma unroll
                for (int r = 0; r < 4; r++) {
                    sc[f][r] = sa[f][r] * SCALE_ATTN + cp[r];
                    mc = fmaxf(mc, sc[f][r]);
                }
            }
            mc = fmaxf(mc, __shfl_xor(mc, 16));
            mc = fmaxf(mc, __shfl_xor(mc, 32));
            if (__any(mc > mrun[qf])) {          // exact skip: corr==1 otherwise
                float mnew = fmaxf(mrun[qf], mc);
                float corr = __expf(mrun[qf] - mnew);  // exp(-inf)=0 first chunk
                mrun[qf] = mnew;
                lrun[qf] *= corr;
                #pragma unroll
                for (int m = 0; m < 2; m++)
                    #pragma unroll
                    for (int r = 0; r < 4; r++)
                        oacc[qf][m][r] *= corr;
            }
            float p[2][4], ls = 0.f;
            #pragma unroll
            for (int f = 0; f < 2; f++)
                #pragma unroll
                for (int r = 0; r < 4; r++) {
                    p[f][r] = __expf(sc[f][r] - mrun[qf]);
                    ls += p[f][r];
                }
            ls += __shfl_xor(ls, 16);
            ls += __shfl_xor(ls, 32);
            lrun[qf] += ls;

            // P -> B-operand of 16x16x16 directly (lane already holds keys 4g+r)
            #pragma unroll
            for (int f = 0; f < 2; f++) {
                union { unsigned u[2]; f16x4 v; } Bp;
                Bp.u[0] = __builtin_bit_cast(unsigned,
                    __builtin_amdgcn_cvt_pkrtz(p[f][0], p[f][1]));
                Bp.u[1] = __builtin_bit_cast(unsigned,
                    __builtin_amdgcn_cvt_pkrtz(p[f][2], p[f][3]));
                #pragma unroll
                for (int m = 0; m < 2; m++)
                    oacc[qf][m] = MFMA16K16(vt[f][m], Bp.v, oacc[qf][m]);
            }
        } // qf
    } // chunk

    // epilogue: normalized per-split O (f16) + (m,l) per query
    f16* obase = opart + (size_t)split * ((size_t)BATCH * NQ * DIMC);
    #pragma unroll
    for (int qf = 0; qf < 2; qf++) {
        float invl = 1.f / lrun[qf];
        int q = q0 + qf * 16 + s;
        f16* orow = obase + ((size_t)(b * NQ + q)) * DIMC + hh * HDIM;
        #pragma unroll
        for (int m = 0; m < 2; m++) {
            f16x4 o;
            #pragma unroll
            for (int r = 0; r < 4; r++) o[r] = (f16)(oacc[qf][m][r] * invl);
            *(f16x4*)(orow + 16 * m + 4 * g) = o;
        }
        if (g == 0)
            ml[((size_t)(split * 32 + bh)) * NQ + q] = make_float2(mrun[qf], lrun[qf]);
    }
}

// ---------------- combine the K-split partials (in place into opart[0]) ----------------
__global__ __launch_bounds__(256) void attn_combine_kernel(
    f16* __restrict__ opart, const float2* __restrict__ ml)
{
    int n = blockIdx.x;              // B*NQ rows
    int b = n >> 12;
    int q = n & 4095;
    int c = threadIdx.x;
    int h = c >> 5;
    int bh = b * NHEADS + h;
    float2 ml0 = ml[((size_t)bh) * NQ + q];
    float2 ml1 = ml[((size_t)(32 + bh)) * NQ + q];
    float M  = fmaxf(ml0.x, ml1.x);
    float w0 = ml0.y * __expf(ml0.x - M);
    float w1 = ml1.y * __expf(ml1.x - M);
    float inv = 1.f / (w0 + w1);
    size_t idx = (size_t)n * DIMC + c;
    float o = (w0 * (float)opart[idx]
             + w1 * (float)opart[idx + (size_t)BATCH * NQ * DIMC]) * inv;
    opart[idx] = (f16)o;
}

extern "C" void kernel_launch(void* const* d_in, const int* in_sizes, int n_in,
                              void* d_out, int out_size, void* d_ws, size_t ws_size,
                              hipStream_t stream)
{
    (void)in_sizes; (void)n_in; (void)out_size; (void)ws_size;
    const float* x    = (const float*)d_in[0];
    const float* xsrc = (const float*)d_in[1];
    const float* loc  = (const float*)d_in[2];
    const float* csrc = (const float*)d_in[3];
    const float* Wq   = (const float*)d_in[4];
    const float* Wk   = (const float*)d_in[5];
    const float* Wv   = (const float*)d_in[6];
    const float* Wsr  = (const float*)d_in[7];
    const float* bsr  = (const float*)d_in[8];
    const float* lng  = (const float*)d_in[9];
    const float* lnb  = (const float*)d_in[10];
    const float* Wp   = (const float*)d_in[11];
    const float* bp   = (const float*)d_in[12];
    // d_in[13]=H(64), d_in[14]=W(64): fixed by setup_inputs; h=w=32 hardcoded.

    const int MS = BATCH * NS * DIMC;     // 1,048,576
    const int MQ = BATCH * NQ * DIMC;     // 4,194,304
    const int WSZ = DIMC * DIMC;          // 65,536

    float* ws      = (float*)d_ws;
    float* feat    = ws;                  // MS f32
    float* xs      = feat + MS;           // MS f32
    float* cnt     = xs + MS;             // 4096
    float* confsum = cnt + BATCH * NS;    // 4096
    float* conf    = confsum + BATCH * NS;// 4096
    f16* q16    = (f16*)(conf + BATCH * NS);  // MQ f16
    f16* k16    = q16 + MQ;               // MS f16
    f16* vt16   = k16 + MS;               // MS f16 (single, transposed)
    f16* opart  = vt16 + MS;              // NSPLIT x MQ f16 (split 0 doubles as abuf)
    float2* ml  = (float2*)(opart + (size_t)NSPLIT * MQ);  // 2*32*NQ float2 = 2 MB
    unsigned short* wsrh = (unsigned short*)(ml + (size_t)NSPLIT * 32 * NQ);
    unsigned short* wsrl = wsrh + WSZ;
    unsigned short* wvh  = wsrl + WSZ;
    unsigned short* wvl  = wvh  + WSZ;
    f16* wq16 = (f16*)(wvl + WSZ);        // 3 x WSZ f16
    f16* wk16 = wq16 + WSZ;
    f16* wp16 = wk16 + WSZ;               // total ~39.5 MB
    float* outp = (float*)d_out;

    hipMemsetAsync(feat, 0, (size_t)MS * sizeof(float), stream);
    hipMemsetAsync(cnt, 0, (size_t)(2 * BATCH * NS) * sizeof(float), stream);

    wprep_kernel<<<dim3(64, 5), 256, 0, stream>>>(
        Wsr, Wv, Wq, Wk, Wp, wsrh, wsrl, wvh, wvl, wq16, wk16, wp16);
    scatter_kernel<<<BATCH * NQ, DIMC, 0, stream>>>(xsrc, loc, csrc, feat, cnt, confsum);
    featfin_kernel<<<BATCH * NS, DIMC, 0, stream>>>(cnt, confsum, feat, conf);
    // Wsr: 4096 rows, NCF=2 -> 16-row blocks, 512 blocks
    mfma_gemm_kernel<2, 0, true ><<<dim3(BATCH * NS / 16, 2), 256, 0, stream>>>(
        feat, wsrh, wsrl, bsr, xs, nullptr);
    ln_kernel<<<BATCH * NS, DIMC, 0, stream>>>(xs, lng, lnb);
    // Wk: 4096 rows, NCF=2
    gemm16_kernel<2, false, true, false><<<dim3(BATCH * NS / 16, 2), 256, 0, stream>>>(
        xs, wk16, nullptr, nullptr, k16);
    // Wv: 4096 rows, NCF=2
    mfma_gemm_kernel<2, 2, false><<<dim3(BATCH * NS / 16, 2), 256, 0, stream>>>(
        xs, wvh, wvl, nullptr, nullptr, vt16);
    // Wq: 16384 rows, NCF=4 -> 32-row blocks, 1024 blocks
    gemm16_kernel<4, false, true, false><<<dim3(BATCH * NQ / 32, 2), 256, 0, stream>>>(
        x, wq16, nullptr, nullptr, q16);
    attn_mfma_kernel<<<NSPLIT * BATCH * NHEADS * (NQ / 128), 256, 0, stream>>>(
        q16, k16, vt16, conf, opart, ml);
    attn_combine_kernel<<<BATCH * NQ, 256, 0, stream>>>(opart, ml);
    // Wp: 16384 rows, NCF=4
    gemm16_kernel<4, true, false, true><<<dim3(BATCH * NQ / 32, 2), 256, 0, stream>>>(
        opart, wp16, bp, outp, nullptr);
}

// Round 10
// 166.882 us; speedup vs baseline: 1.9258x; 1.3781x over previous
//
#include <hip/hip_runtime.h>
#include <math.h>

#define DIMC   256
#define NQ     4096
#define BATCH  4
#define NS     1024    // (H/SR)*(W/SR) = 32*32
#define WG     32
#define HG     32
#define NHEADS 8
#define HDIM   32
#define TILEK  128     // keys staged per LDS tile
#define KSTRIDE 40     // f16 per K row in LDS (80B, 16B-aligned, uniform banks)
#define VSTRIDE 136    // f16 per Vt row in LDS (272B, 8B-aligned, 2-way = free)
#define SCALE_ATTN 0.17677669529663687f  // 32^-0.5

typedef _Float16 f16;
typedef __attribute__((ext_vector_type(8))) __bf16    bf16x8;
typedef __attribute__((ext_vector_type(8))) _Float16  f16x8;
typedef __attribute__((ext_vector_type(4))) _Float16  f16x4;
typedef __attribute__((ext_vector_type(4))) float     f32x4;

#define MFMA16B(A, B, C)  __builtin_amdgcn_mfma_f32_16x16x32_bf16((A), (B), (C), 0, 0, 0)
#define MFMA16F(A, B, C)  __builtin_amdgcn_mfma_f32_16x16x32_f16((A), (B), (C), 0, 0, 0)
#define MFMA16K16(A, B, C) __builtin_amdgcn_mfma_f32_16x16x16f16((A), (B), (C), 0, 0, 0)

static __device__ __forceinline__ unsigned short bf16_hi(float v) {
    return __builtin_bit_cast(unsigned short, (__bf16)v);
}

// ---------------- scatter: token2map segment-sum ----------------
__global__ __launch_bounds__(DIMC) void scatter_kernel(
    const float* __restrict__ xsrc, const float* __restrict__ loc,
    const float* __restrict__ csrc, float* __restrict__ feat,
    float* __restrict__ cnt, float* __restrict__ confsum)
{
    int token = blockIdx.x;          // B*NQ tokens
    int b = token >> 12;             // NQ = 4096
    int c = threadIdx.x;
    float lx = loc[token * 2 + 0];
    float ly = loc[token * 2 + 1];
    lx = fminf(fmaxf(lx, 0.f), 1.f) * (float)(WG - 1);
    ly = fminf(fmaxf(ly, 0.f), 1.f) * (float)(HG - 1);
    int ix = (int)rintf(lx);         // round-half-even, matches jnp.round
    int iy = (int)rintf(ly);
    int cell = b * NS + iy * WG + ix;
    atomicAdd(&feat[cell * DIMC + c], xsrc[token * DIMC + c]);
    if (c == 0) {
        atomicAdd(&cnt[cell], 1.f);
        atomicAdd(&confsum[cell], csrc[token]);
    }
}

// ---------------- finalize: feat /= (cnt+eps), mask; conf map ----------------
__global__ __launch_bounds__(DIMC) void featfin_kernel(
    const float* __restrict__ cnt, const float* __restrict__ confsum,
    float* __restrict__ feat, float* __restrict__ conf)
{
    int m = blockIdx.x;              // B*NS cells
    int c = threadIdx.x;
    float cv = cnt[m];
    float inv = (cv > 0.f) ? 1.f / (cv + 1e-6f) : 0.f;
    feat[m * DIMC + c] *= inv;
    if (c == 0) conf[m] = confsum[m] * inv;
}

// ---------------- weight prep: Wsr,Wv -> bf16 hi/lo; Wq,Wk,Wp -> f16 ----------------
__global__ __launch_bounds__(256) void wprep_kernel(
    const float* __restrict__ Wsr, const float* __restrict__ Wv,
    const float* __restrict__ Wq, const float* __restrict__ Wk,
    const float* __restrict__ Wp,
    unsigned short* __restrict__ wsrh, unsigned short* __restrict__ wsrl,
    unsigned short* __restrict__ wvh, unsigned short* __restrict__ wvl,
    f16* __restrict__ wq16, f16* __restrict__ wk16, f16* __restrict__ wp16)
{
    int i = (blockIdx.x * 256 + threadIdx.x) * 4;   // grid.x = 64 -> 65536 elems
    int m = blockIdx.y;
    if (m < 2) {
        const float* W = m ? Wv : Wsr;
        unsigned short* H = m ? wvh : wsrh;
        unsigned short* L = m ? wvl : wsrl;
        float4 v = *(const float4*)(W + i);
        float vv[4] = {v.x, v.y, v.z, v.w};
        ushort4 h, l;
        unsigned short* hp = &h.x; unsigned short* lp = &l.x;
        #pragma unroll
        for (int j = 0; j < 4; j++) {
            __bf16 hb = (__bf16)vv[j];
            hp[j] = __builtin_bit_cast(unsigned short, hb);
            lp[j] = bf16_hi(vv[j] - (float)hb);
        }
        *(ushort4*)(H + i) = h;
        *(ushort4*)(L + i) = l;
    } else {
        const float* W = (m == 2) ? Wq : (m == 3) ? Wk : Wp;
        f16* O = (m == 2) ? wq16 : (m == 3) ? wk16 : wp16;
        float4 v = *(const float4*)(W + i);
        f16x4 h = {(f16)v.x, (f16)v.y, (f16)v.z, (f16)v.w};
        *(f16x4*)(O + i) = h;
    }
}

// ---------------- bf16x2-split MFMA GEMM (exact-ish): Wsr, Wv ----------------
// NCF = col-frags per wave; rows/block = 64/(8/NCF). EPI: 0 = f32 row-major;
// 2 = single f16 transposed (V): out[(b*256+c)*1024+key].
template <int NCF, int EPI, bool HASBIAS>
__global__ __launch_bounds__(256) void mfma_gemm_kernel(
    const float* __restrict__ A,
    const unsigned short* __restrict__ Whi, const unsigned short* __restrict__ Wlo,
    const float* __restrict__ bias, float* __restrict__ outF,
    f16* __restrict__ o16a)
{
    constexpr int WPS = 8 / NCF;              // col-waves per 16-row strip
    constexpr int RB  = 64 / WPS;             // rows per block
    int r0 = blockIdx.x * RB;
    int c0 = blockIdx.y * 128;
    int wave = threadIdx.x >> 6;
    int lane = threadIdx.x & 63;
    int s = lane & 15, g = lane >> 4;
    int strip = wave / WPS, cg = wave % WPS;
    int arow = r0 + strip * 16 + s;
    int cb = c0 + cg * NCF * 16;
    const float* ap = A + (size_t)arow * DIMC + 8 * g;

    f32x4 acc[NCF];
    #pragma unroll
    for (int cf = 0; cf < NCF; cf++) {
        float bv = HASBIAS ? bias[cb + cf * 16 + s] : 0.f;
        acc[cf] = (f32x4){bv, bv, bv, bv};
    }

    #pragma unroll
    for (int kk = 0; kk < 8; kk++) {
        float4 a0 = *(const float4*)(ap + kk * 32);
        float4 a1 = *(const float4*)(ap + kk * 32 + 4);
        float av[8] = {a0.x, a0.y, a0.z, a0.w, a1.x, a1.y, a1.z, a1.w};
        bf16x8 ah, al;
        #pragma unroll
        for (int j = 0; j < 8; j++) {
            __bf16 hb = (__bf16)av[j];
            ah[j] = hb;
            al[j] = (__bf16)(av[j] - (float)hb);
        }
        #pragma unroll
        for (int cf = 0; cf < NCF; cf++) {
            size_t woff = (size_t)(cb + cf * 16 + s) * DIMC + kk * 32 + 8 * g;
            bf16x8 bh = *(const bf16x8*)(Whi + woff);
            bf16x8 bl = *(const bf16x8*)(Wlo + woff);
            acc[cf] = MFMA16B(ah, bh, acc[cf]);
            acc[cf] = MFMA16B(al, bh, acc[cf]);
            acc[cf] = MFMA16B(ah, bl, acc[cf]);
        }
    }

    int rbase = r0 + strip * 16 + 4 * g;      // output rows rbase..rbase+3
    if (EPI == 0) {
        #pragma unroll
        for (int cf = 0; cf < NCF; cf++) {
            int c = cb + cf * 16 + s;
            #pragma unroll
            for (int r = 0; r < 4; r++)
                outF[(size_t)(rbase + r) * DIMC + c] = acc[cf][r];
        }
    } else {
        int b = rbase >> 10;                  // row blocks never cross batch
        int key0 = rbase & 1023;
        #pragma unroll
        for (int cf = 0; cf < NCF; cf++) {
            int c = cb + cf * 16 + s;
            f16x4 h;
            #pragma unroll
            for (int r = 0; r < 4; r++) h[r] = (f16)acc[cf][r];
            size_t off = ((size_t)(b * DIMC + c)) * NS + key0;
            *(f16x4*)(o16a + off) = h;
        }
    }
}

// ---------------- single-product fp16 GEMM: Wq, Wk, Wp ----------------
// NCF as above. A16: A is f16. OUT16: f16 out.
template <int NCF, bool A16, bool OUT16, bool HASBIAS>
__global__ __launch_bounds__(256) void gemm16_kernel(
    const void* __restrict__ Ain, const f16* __restrict__ W,
    const float* __restrict__ bias, float* __restrict__ outF,
    f16* __restrict__ out16)
{
    constexpr int WPS = 8 / NCF;
    constexpr int RB  = 64 / WPS;
    int r0 = blockIdx.x * RB;
    int c0 = blockIdx.y * 128;
    int wave = threadIdx.x >> 6;
    int lane = threadIdx.x & 63;
    int s = lane & 15, g = lane >> 4;
    int strip = wave / WPS, cg = wave % WPS;
    int arow = r0 + strip * 16 + s;
    int cb = c0 + cg * NCF * 16;

    f32x4 acc[NCF];
    #pragma unroll
    for (int cf = 0; cf < NCF; cf++) {
        float bv = HASBIAS ? bias[cb + cf * 16 + s] : 0.f;
        acc[cf] = (f32x4){bv, bv, bv, bv};
    }

    #pragma unroll
    for (int kk = 0; kk < 8; kk++) {
        f16x8 a;
        if (A16) {
            a = *(const f16x8*)((const f16*)Ain + (size_t)arow * DIMC + kk * 32 + 8 * g);
        } else {
            const float* ap = (const float*)Ain + (size_t)arow * DIMC + kk * 32 + 8 * g;
            float4 a0 = *(const float4*)ap;
            float4 a1 = *(const float4*)(ap + 4);
            a = (f16x8){(f16)a0.x, (f16)a0.y, (f16)a0.z, (f16)a0.w,
                        (f16)a1.x, (f16)a1.y, (f16)a1.z, (f16)a1.w};
        }
        #pragma unroll
        for (int cf = 0; cf < NCF; cf++) {
            f16x8 bfrag = *(const f16x8*)(W + (size_t)(cb + cf * 16 + s) * DIMC + kk * 32 + 8 * g);
            acc[cf] = MFMA16F(a, bfrag, acc[cf]);
        }
    }

    int rbase = r0 + strip * 16 + 4 * g;
    #pragma unroll
    for (int cf = 0; cf < NCF; cf++) {
        int c = cb + cf * 16 + s;
        #pragma unroll
        for (int r = 0; r < 4; r++) {
            if (OUT16) out16[(size_t)(rbase + r) * DIMC + c] = (f16)acc[cf][r];
            else       outF [(size_t)(rbase + r) * DIMC + c] = acc[cf][r];
        }
    }
}

// ---------------- layernorm in place over last dim ----------------
__global__ __launch_bounds__(DIMC) void ln_kernel(
    float* __restrict__ xs, const float* __restrict__ g, const float* __restrict__ b)
{
    int m = blockIdx.x;
    int c = threadIdx.x;
    float v = xs[(size_t)m * DIMC + c];
    float s = v, q = v * v;
    #pragma unroll
    for (int off = 32; off > 0; off >>= 1) {
        s += __shfl_xor(s, off);
        q += __shfl_xor(q, off);
    }
    __shared__ float sh1[4], sh2[4];
    int wid = c >> 6, lane = c & 63;
    if (lane == 0) { sh1[wid] = s; sh2[wid] = q; }
    __syncthreads();
    s = sh1[0] + sh1[1] + sh1[2] + sh1[3];
    q = sh2[0] + sh2[1] + sh2[2] + sh2[3];
    float mu  = s * (1.f / DIMC);
    float var = q * (1.f / DIMC) - mu * mu;
    xs[(size_t)m * DIMC + c] = (v - mu) * rsqrtf(var + 1e-5f) * g[c] + b[c];
}

// ---------------- MFMA flash attention (fp16, LDS-staged K/Vt) ----------------
// 32 q/wave, 32-key chunks (R8 compute shape). K/Vt staged per 128-key tile in
// LDS, shared by all 4 waves; double-buffered with early global-load issue.
__global__ __launch_bounds__(256) void attn_mfma_kernel(
    const f16* __restrict__ qbuf, const f16* __restrict__ kbuf,
    const f16* __restrict__ vt16, const float* __restrict__ conf,
    f16* __restrict__ abuf)
{
    __shared__ f16 Ks[2][TILEK * KSTRIDE];   // 2 x 10240 B
    __shared__ f16 Vs[2][HDIM * VSTRIDE];    // 2 x 8704 B

    int blk  = blockIdx.x;            // B*H*(NQ/128) = 1024
    int qt   = blk & 31;              // NQ/128 = 32
    int bh   = blk >> 5;
    int hh   = bh & (NHEADS - 1);
    int b    = bh >> 3;
    int wave = threadIdx.x >> 6;
    int lane = threadIdx.x & 63;
    int s = lane & 15, g = lane >> 4;
    int q0 = qt * 128 + wave * 32;
    int tid = threadIdx.x;

    // staging decomposition: K: 512 x 16B chunks (r=c>>2, h=c&3);
    //                        V: 512 x 16B chunks (r=c>>4, j=c&15)
    int kr0 = tid >> 2, khc = tid & 3;       // + chunk tid+256 -> row +64
    int vr0 = tid >> 4, vjc = tid & 15;      // + chunk tid+256 -> row +16
    const f16* kgb = kbuf + ((size_t)(b * NS)) * DIMC + hh * HDIM;
    const f16* vgb = vt16 + ((size_t)(bh * HDIM)) * NS;

    // Q fragments (B-operand for S^T): lane holds Q[q0+qf*16+s][d=8g+j]
    f16x8 qh[2];
    #pragma unroll
    for (int qf = 0; qf < 2; qf++)
        qh[qf] = *(const f16x8*)(qbuf +
            ((size_t)(b * NQ + q0 + qf * 16 + s)) * DIMC + hh * HDIM + 8 * g);

    f32x4 oacc[2][2];
    #pragma unroll
    for (int qf = 0; qf < 2; qf++)
        #pragma unroll
        for (int m = 0; m < 2; m++)
            oacc[qf][m] = (f32x4){0.f, 0.f, 0.f, 0.f};
    float mrun[2] = {-INFINITY, -INFINITY};
    float lrun[2] = {0.f, 0.f};

    const float* cfb = conf + b * NS + 4 * g;

    // prologue: stage tile 0
    f16x8 kA, kB, vA, vB;
    kA = *(const f16x8*)(kgb + (size_t)kr0 * DIMC + khc * 8);
    kB = *(const f16x8*)(kgb + (size_t)(kr0 + 64) * DIMC + khc * 8);
    vA = *(const f16x8*)(vgb + (size_t)vr0 * NS + vjc * 8);
    vB = *(const f16x8*)(vgb + (size_t)(vr0 + 16) * NS + vjc * 8);
    *(f16x8*)(&Ks[0][kr0 * KSTRIDE + khc * 8]) = kA;
    *(f16x8*)(&Ks[0][(kr0 + 64) * KSTRIDE + khc * 8]) = kB;
    *(f16x8*)(&Vs[0][vr0 * VSTRIDE + vjc * 8]) = vA;
    *(f16x8*)(&Vs[0][(vr0 + 16) * VSTRIDE + vjc * 8]) = vB;
    __syncthreads();

    for (int t = 0; t < NS / TILEK; t++) {
        int cur = t & 1;
        if (t < NS / TILEK - 1) {            // issue next-tile loads early (T14)
            int kt = (t + 1) * TILEK;
            kA = *(const f16x8*)(kgb + (size_t)(kt + kr0) * DIMC + khc * 8);
            kB = *(const f16x8*)(kgb + (size_t)(kt + kr0 + 64) * DIMC + khc * 8);
            vA = *(const f16x8*)(vgb + (size_t)vr0 * NS + kt + vjc * 8);
            vB = *(const f16x8*)(vgb + (size_t)(vr0 + 16) * NS + kt + vjc * 8);
        }
        #pragma unroll
        for (int kc = 0; kc < TILEK / 32; kc++) {
            int krow = kc * 32;
            int k0g  = t * TILEK + krow;     // global key index (conf)
            // K fragments from LDS: lane holds K[krow+16f+s][d=8g+j]
            f16x8 khf[2];
            #pragma unroll
            for (int f = 0; f < 2; f++)
                khf[f] = *(const f16x8*)(&Ks[cur][(krow + 16 * f + s) * KSTRIDE + 8 * g]);
            // V^T fragments from LDS: vtf[f][m] = Vt[16m+s][krow+16f+4g+j]
            f16x4 vtf[2][2];
            #pragma unroll
            for (int f = 0; f < 2; f++)
                #pragma unroll
                for (int m = 0; m < 2; m++)
                    vtf[f][m] = *(const f16x4*)(&Vs[cur][(16 * m + s) * VSTRIDE
                                                         + krow + 16 * f + 4 * g]);
            // conf for this lane's score slots: keys k0g + 16f + 4g + r
            float4 cq[2];
            #pragma unroll
            for (int f = 0; f < 2; f++)
                cq[f] = *(const float4*)(cfb + k0g + 16 * f);

            #pragma unroll
            for (int qf = 0; qf < 2; qf++) {
                f32x4 sa[2];
                #pragma unroll
                for (int f = 0; f < 2; f++) {
                    f32x4 z = (f32x4){0.f, 0.f, 0.f, 0.f};
                    sa[f] = MFMA16F(khf[f], qh[qf], z);
                }
                float sc[2][4], mc = -INFINITY;
                #pragma unroll
                for (int f = 0; f < 2; f++) {
                    const float* cp = &cq[f].x;
                    #pragma unroll
                    for (int r = 0; r < 4; r++) {
                        sc[f][r] = sa[f][r] * SCALE_ATTN + cp[r];
                        mc = fmaxf(mc, sc[f][r]);
                    }
                }
                mc = fmaxf(mc, __shfl_xor(mc, 16));
                mc = fmaxf(mc, __shfl_xor(mc, 32));
                if (__any(mc > mrun[qf])) {      // exact skip: corr==1 otherwise
                    float mnew = fmaxf(mrun[qf], mc);
                    float corr = __expf(mrun[qf] - mnew);  // exp(-inf)=0 first chunk
                    mrun[qf] = mnew;
                    lrun[qf] *= corr;
                    #pragma unroll
                    for (int m = 0; m < 2; m++)
                        #pragma unroll
                        for (int r = 0; r < 4; r++)
                            oacc[qf][m][r] *= corr;
                }
                float p[2][4], ls = 0.f;
                #pragma unroll
                for (int f = 0; f < 2; f++)
                    #pragma unroll
                    for (int r = 0; r < 4; r++) {
                        p[f][r] = __expf(sc[f][r] - mrun[qf]);
                        ls += p[f][r];
                    }
                ls += __shfl_xor(ls, 16);
                ls += __shfl_xor(ls, 32);
                lrun[qf] += ls;

                // P -> B-operand of 16x16x16 directly (lane already holds keys 4g+r)
                #pragma unroll
                for (int f = 0; f < 2; f++) {
                    union { unsigned u[2]; f16x4 v; } Bp;
                    Bp.u[0] = __builtin_bit_cast(unsigned,
                        __builtin_amdgcn_cvt_pkrtz(p[f][0], p[f][1]));
                    Bp.u[1] = __builtin_bit_cast(unsigned,
                        __builtin_amdgcn_cvt_pkrtz(p[f][2], p[f][3]));
                    #pragma unroll
                    for (int m = 0; m < 2; m++)
                        oacc[qf][m] = MFMA16K16(vtf[f][m], Bp.v, oacc[qf][m]);
                }
            } // qf
        } // kc
        if (t < NS / TILEK - 1) {
            __syncthreads();                 // all waves done reading buf cur^1
            int nxt = cur ^ 1;
            *(f16x8*)(&Ks[nxt][kr0 * KSTRIDE + khc * 8]) = kA;
            *(f16x8*)(&Ks[nxt][(kr0 + 64) * KSTRIDE + khc * 8]) = kB;
            *(f16x8*)(&Vs[nxt][vr0 * VSTRIDE + vjc * 8]) = vA;
            *(f16x8*)(&Vs[nxt][(vr0 + 16) * VSTRIDE + vjc * 8]) = vB;
            __syncthreads();
        }
    } // tile

    // epilogue: oacc[qf][m][r] = O^T[d=16m+4g+r][q=q0+16qf+s]; f16 out
    #pragma unroll
    for (int qf = 0; qf < 2; qf++) {
        float invl = 1.f / lrun[qf];
        f16* orow = abuf + ((size_t)(b * NQ + q0 + qf * 16 + s)) * DIMC + hh * HDIM;
        #pragma unroll
        for (int m = 0; m < 2; m++) {
            f16x4 o;
            #pragma unroll
            for (int r = 0; r < 4; r++) o[r] = (f16)(oacc[qf][m][r] * invl);
            *(f16x4*)(orow + 16 * m + 4 * g) = o;
        }
    }
}

extern "C" void kernel_launch(void* const* d_in, const int* in_sizes, int n_in,
                              void* d_out, int out_size, void* d_ws, size_t ws_size,
                              hipStream_t stream)
{
    (void)in_sizes; (void)n_in; (void)out_size; (void)ws_size;
    const float* x    = (const float*)d_in[0];
    const float* xsrc = (const float*)d_in[1];
    const float* loc  = (const float*)d_in[2];
    const float* csrc = (const float*)d_in[3];
    const float* Wq   = (const float*)d_in[4];
    const float* Wk   = (const float*)d_in[5];
    const float* Wv   = (const float*)d_in[6];
    const float* Wsr  = (const float*)d_in[7];
    const float* bsr  = (const float*)d_in[8];
    const float* lng  = (const float*)d_in[9];
    const float* lnb  = (const float*)d_in[10];
    const float* Wp   = (const float*)d_in[11];
    const float* bp   = (const float*)d_in[12];
    // d_in[13]=H(64), d_in[14]=W(64): fixed by setup_inputs; h=w=32 hardcoded.

    const int MS = BATCH * NS * DIMC;     // 1,048,576
    const int MQ = BATCH * NQ * DIMC;     // 4,194,304
    const int WSZ = DIMC * DIMC;          // 65,536

    float* ws      = (float*)d_ws;
    float* feat    = ws;                  // MS f32
    float* xs      = feat + MS;           // MS f32
    float* cnt     = xs + MS;             // 4096
    float* confsum = cnt + BATCH * NS;    // 4096
    float* conf    = confsum + BATCH * NS;// 4096
    f16* q16    = (f16*)(conf + BATCH * NS);  // MQ f16
    f16* k16    = q16 + MQ;               // MS f16
    f16* vt16   = k16 + MS;               // MS f16 (single, transposed)
    f16* abuf16 = vt16 + MS;              // MQ f16
    unsigned short* wsrh = (unsigned short*)(abuf16 + MQ);  // 4 x WSZ bf16
    unsigned short* wsrl = wsrh + WSZ;
    unsigned short* wvh  = wsrl + WSZ;
    unsigned short* wvl  = wvh  + WSZ;
    f16* wq16 = (f16*)(wvl + WSZ);        // 3 x WSZ f16
    f16* wk16 = wq16 + WSZ;
    f16* wp16 = wk16 + WSZ;               // total ~31 MB
    float* outp = (float*)d_out;

    hipMemsetAsync(feat, 0, (size_t)MS * sizeof(float), stream);
    hipMemsetAsync(cnt, 0, (size_t)(2 * BATCH * NS) * sizeof(float), stream);

    wprep_kernel<<<dim3(64, 5), 256, 0, stream>>>(
        Wsr, Wv, Wq, Wk, Wp, wsrh, wsrl, wvh, wvl, wq16, wk16, wp16);
    scatter_kernel<<<BATCH * NQ, DIMC, 0, stream>>>(xsrc, loc, csrc, feat, cnt, confsum);
    featfin_kernel<<<BATCH * NS, DIMC, 0, stream>>>(cnt, confsum, feat, conf);
    mfma_gemm_kernel<2, 0, true ><<<dim3(BATCH * NS / 16, 2), 256, 0, stream>>>(
        feat, wsrh, wsrl, bsr, xs, nullptr);
    ln_kernel<<<BATCH * NS, DIMC, 0, stream>>>(xs, lng, lnb);
    gemm16_kernel<2, false, true, false><<<dim3(BATCH * NS / 16, 2), 256, 0, stream>>>(
        xs, wk16, nullptr, nullptr, k16);
    mfma_gemm_kernel<2, 2, false><<<dim3(BATCH * NS / 16, 2), 256, 0, stream>>>(
        xs, wvh, wvl, nullptr, nullptr, vt16);
    gemm16_kernel<4, false, true, false><<<dim3(BATCH * NQ / 32, 2), 256, 0, stream>>>(
        x, wq16, nullptr, nullptr, q16);
    attn_mfma_kernel<<<BATCH * NHEADS * (NQ / 128), 256, 0, stream>>>(
        q16, k16, vt16, conf, abuf16);
    gemm16_kernel<4, true, false, true><<<dim3(BATCH * NQ / 32, 2), 256, 0, stream>>>(
        abuf16, wp16, bp, outp, nullptr);
}